// Round 2
// baseline (3678.561 us; speedup 1.0000x reference)
//
#include <hip/hip_runtime.h>

#define D 128
#define NH 8

typedef __bf16 bf16x8 __attribute__((ext_vector_type(8)));
typedef unsigned short ushortx8 __attribute__((ext_vector_type(8)));
typedef float floatx4 __attribute__((ext_vector_type(4)));

__device__ __forceinline__ float bf2f(unsigned short u) {
  union { unsigned int i; float f; } x; x.i = ((unsigned int)u) << 16; return x.f;
}
__device__ __forceinline__ unsigned short f2bf(float f) {
  union { float f; unsigned int i; } x; x.f = f;
  unsigned int i = x.i;
  return (unsigned short)((i + 0x7FFFu + ((i >> 16) & 1u)) >> 16);
}

// ---------------------------------------------------------------- zero init
__global__ void k_zero(float* __restrict__ p, long long n) {
  long long i = ((long long)blockIdx.x * blockDim.x + threadIdx.x) * 4;
  long long stride = (long long)gridDim.x * blockDim.x * 4;
  for (; i + 3 < n; i += stride) {
    *(float4*)(p + i) = make_float4(0.f, 0.f, 0.f, 0.f);
  }
}

// ---------------------------------------------------------------- projections
// P[combo][N][128] (bf16) = fp32 X @ fp32 W + b ; combo = proj*3 + m (0=K,1=Q,2=V)
__global__ __launch_bounds__(256) void k_proj(
    const float* __restrict__ x0, const float* __restrict__ x1,
    const float* __restrict__ x2,
    const float* __restrict__ Wk, const float* __restrict__ bk,
    const float* __restrict__ Wq, const float* __restrict__ bq,
    const float* __restrict__ Wv, const float* __restrict__ bv,
    unsigned short* __restrict__ P, int N)
{
  __shared__ __attribute__((aligned(16))) unsigned short Wt[128 * 136];
  int combo = blockIdx.y;
  int m = combo % 3, proj = combo / 3;
  const float* X = (m == 0) ? x0 : ((m == 1) ? x1 : x2);
  const float* W = (proj == 0) ? Wk : ((proj == 1) ? Wq : Wv);
  const float* B = (proj == 0) ? bk : ((proj == 1) ? bq : bv);
  int tid = threadIdx.x;
  for (int idx = tid; idx < 128 * 128; idx += 256) {
    int k = idx >> 7, c = idx & 127;
    Wt[c * 136 + k] = f2bf(W[idx]);       // transposed: Wt[col][k]
  }
  __syncthreads();
  int wave = tid >> 6, lane = tid & 63;
  int quad = lane >> 4, l16 = lane & 15;
  int row0 = blockIdx.x * 64 + wave * 16;
  int arow = row0 + l16; if (arow >= N) arow = N - 1;
  const float* ap = X + (size_t)arow * D;
  floatx4 acc[8];
#pragma unroll
  for (int ct = 0; ct < 8; ct++) acc[ct] = (floatx4)0.f;
#pragma unroll
  for (int kk = 0; kk < 128; kk += 32) {
    float4 f0 = *(const float4*)(ap + kk + quad * 8);
    float4 f1 = *(const float4*)(ap + kk + quad * 8 + 4);
    ushortx8 uu;
    uu[0]=f2bf(f0.x); uu[1]=f2bf(f0.y); uu[2]=f2bf(f0.z); uu[3]=f2bf(f0.w);
    uu[4]=f2bf(f1.x); uu[5]=f2bf(f1.y); uu[6]=f2bf(f1.z); uu[7]=f2bf(f1.w);
    bf16x8 af = __builtin_bit_cast(bf16x8, uu);
#pragma unroll
    for (int ct = 0; ct < 8; ct++) {
      uint4 bu = *(const uint4*)(&Wt[(ct * 16 + l16) * 136 + kk + quad * 8]);
      bf16x8 bf = __builtin_bit_cast(bf16x8, bu);
      acc[ct] = __builtin_amdgcn_mfma_f32_16x16x32_bf16(af, bf, acc[ct], 0, 0, 0);
    }
  }
  unsigned short* Pout = P + (size_t)combo * N * D;
#pragma unroll
  for (int ct = 0; ct < 8; ct++) {
    int col = ct * 16 + l16;
    float bias = B[col];
#pragma unroll
    for (int i = 0; i < 4; i++) {
      int r = row0 + quad * 4 + i;
      if (r < N) Pout[(size_t)r * D + col] = f2bf(acc[ct][i] + bias);
    }
  }
}

// ---------------------------------------------------------------- edge att+lam
__global__ __launch_bounds__(256) void k_edge_att(
    const unsigned short* __restrict__ P, const int* __restrict__ src,
    const int* __restrict__ dst,
    const float* __restrict__ rel_att, const float* __restrict__ rel_pri,
    const float* __restrict__ wm0, const float* __restrict__ wm1,
    const float* __restrict__ wm2,
    float* __restrict__ att_ws, float* __restrict__ lam_ws,
    float* __restrict__ sumA, float* __restrict__ sumAl, int N, int E)
{
  __shared__ __attribute__((aligned(16))) float Alds[8 * 260];   // pad: h-stride 260
  __shared__ __attribute__((aligned(16))) float Wlds[3 * 8 * 260];
  int tid = threadIdx.x;
  for (int idx = tid; idx < 2048; idx += 256) {
    int h = idx >> 8, r = idx & 255;
    Alds[h * 260 + r] = rel_att[idx];
    Wlds[0 * 2080 + h * 260 + r] = wm0[idx];
    Wlds[1 * 2080 + h * 260 + r] = wm1[idx];
    Wlds[2 * 2080 + h * 260 + r] = wm2[idx];
  }
  __syncthreads();
  int gid = blockIdx.x * 256 + tid;
  int e = gid >> 3, h = gid & 7;
  if (e >= E) return;
  int s = src[e], d = dst[e];
  float pri = rel_pri[h] * 2.5f;   // rel_pri / sqrt(16) * 10
  float attv[3], lamv[3];
#pragma unroll
  for (int m = 0; m < 3; m++) {
    const unsigned short* kp = P + ((size_t)m * N + s) * D + h * 16;
    const unsigned short* qp = P + ((size_t)(3 + m) * N + d) * D + h * 16;
    union { uint4 u; unsigned short us[8]; } k0, k1, q0, q1;
    k0.u = *(const uint4*)kp;  k1.u = *(const uint4*)(kp + 8);
    q0.u = *(const uint4*)qp;  q1.u = *(const uint4*)(qp + 8);
    float kr[16], qr[16];
#pragma unroll
    for (int j = 0; j < 8; j++) {
      kr[j] = bf2f(k0.us[j]); kr[8 + j] = bf2f(k1.us[j]);
      qr[j] = bf2f(q0.us[j]); qr[8 + j] = bf2f(q1.us[j]);
    }
    float atm = 0.f, lmm = 0.f;
#pragma unroll
    for (int f4 = 0; f4 < 4; f4++) {
      float sax=0.f, say=0.f, saz=0.f, saw=0.f;
      float swx=0.f, swy=0.f, swz=0.f, sww=0.f;
#pragma unroll
      for (int dd = 0; dd < 16; dd++) {
        float kd = kr[dd];
        float4 a4 = *(const float4*)(&Alds[h * 260 + dd * 16 + f4 * 4]);
        float4 w4 = *(const float4*)(&Wlds[m * 2080 + h * 260 + dd * 16 + f4 * 4]);
        sax += kd * a4.x; say += kd * a4.y; saz += kd * a4.z; saw += kd * a4.w;
        swx += kd * w4.x; swy += kd * w4.y; swz += kd * w4.z; sww += kd * w4.w;
      }
      atm += sax*qr[f4*4+0] + say*qr[f4*4+1] + saz*qr[f4*4+2] + saw*qr[f4*4+3];
      lmm += swx*qr[f4*4+0] + swy*qr[f4*4+1] + swz*qr[f4*4+2] + sww*qr[f4*4+3];
    }
    attv[m] = atm * pri;
    lamv[m] = lmm;
  }
  size_t E8 = (size_t)E * 8;
  size_t eh = (size_t)e * 8 + h;
  att_ws[eh] = attv[0]; att_ws[E8 + eh] = attv[1]; att_ws[2 * E8 + eh] = attv[2];
  // lam = softmax over the 3 modalities (edge-local)
  float mx = fmaxf(lamv[0], fmaxf(lamv[1], lamv[2]));
  float e0 = __expf(lamv[0] - mx), e1 = __expf(lamv[1] - mx), e2 = __expf(lamv[2] - mx);
  float inv = 1.f / (e0 + e1 + e2);
  lam_ws[eh] = e0 * inv; lam_ws[E8 + eh] = e1 * inv; lam_ws[2 * E8 + eh] = e2 * inv;
  float align = -(fabsf(attv[0]-attv[1]) + fabsf(attv[0]-attv[2]) + fabsf(attv[1]-attv[2])) * (1.f/3.f);
  size_t nh = (size_t)d * 8 + h;
  atomicAdd(&sumA[nh], __expf(attv[0]));
  atomicAdd(&sumA[(size_t)N * 8 + nh], __expf(attv[1]));
  atomicAdd(&sumA[2 * (size_t)N * 8 + nh], __expf(attv[2]));
  atomicAdd(&sumAl[nh], __expf(align));
}

// ---------------------------------------------------------------- beta / t
__global__ __launch_bounds__(256) void k_edge_beta(
    const float* __restrict__ att_ws, const float* __restrict__ lam_ws,
    const float* __restrict__ sumA, const float* __restrict__ sumAl,
    const int* __restrict__ dst, float* __restrict__ t_ws, float* __restrict__ sumT,
    int N, int E)
{
  int gid = blockIdx.x * 256 + threadIdx.x;
  int e = gid >> 3, h = gid & 7;
  if (e >= E) return;
  int d = dst[e];
  size_t E8 = (size_t)E * 8;
  size_t eh = (size_t)e * 8 + h;
  size_t nh = (size_t)d * 8 + h;
  float a0 = att_ws[eh], a1 = att_ws[E8 + eh], a2 = att_ws[2 * E8 + eh];
  float l0 = lam_ws[eh], l1 = lam_ws[E8 + eh], l2 = lam_ws[2 * E8 + eh];
  float sm0 = __expf(a0) / sumA[nh];
  float sm1 = __expf(a1) / sumA[(size_t)N * 8 + nh];
  float sm2 = __expf(a2) / sumA[2 * (size_t)N * 8 + nh];
  float beta1 = l0 * sm0 + l1 * sm1 + l2 * sm2;
  float align = -(fabsf(a0-a1) + fabsf(a0-a2) + fabsf(a1-a2)) * (1.f/3.f);
  float beta2 = __expf(align) / sumAl[nh];
  float t = beta1 * beta2;
  t_ws[eh] = t;
  atomicAdd(&sumT[nh], __expf(t));
}

// ---------------------------------------------------------------- aggregate
__global__ __launch_bounds__(256) void k_edge_agg(
    const unsigned short* __restrict__ P, const float* __restrict__ t_ws,
    const float* __restrict__ sumT,
    const int* __restrict__ src, const int* __restrict__ dst,
    const float* __restrict__ rel_msg, float* __restrict__ hagg, int N, int E)
{
  __shared__ __attribute__((aligned(16))) float Mlds[8 * 260];
  int tid = threadIdx.x;
  for (int idx = tid; idx < 2048; idx += 256) {
    int h = idx >> 8, r = idx & 255;
    Mlds[h * 260 + r] = rel_msg[idx];
  }
  __syncthreads();
  int gid = blockIdx.x * 256 + tid;
  int e = gid >> 3, h = gid & 7;
  if (e >= E) return;
  int s = src[e], d = dst[e];
  size_t eh = (size_t)e * 8 + h;
  float beta = __expf(t_ws[eh]) / sumT[(size_t)d * 8 + h];
#pragma unroll
  for (int m = 0; m < 3; m++) {
    const unsigned short* vp = P + ((size_t)(6 + m) * N + s) * D + h * 16;
    union { uint4 u; unsigned short us[8]; } v0, v1;
    v0.u = *(const uint4*)vp; v1.u = *(const uint4*)(vp + 8);
    float v[16];
#pragma unroll
    for (int j = 0; j < 8; j++) { v[j] = bf2f(v0.us[j]); v[8 + j] = bf2f(v1.us[j]); }
    float* hb = hagg + ((size_t)m * N + d) * D + h * 16;
#pragma unroll
    for (int f4 = 0; f4 < 4; f4++) {
      float ax=0.f, ay=0.f, az=0.f, aw=0.f;
#pragma unroll
      for (int dd = 0; dd < 16; dd++) {
        float4 m4 = *(const float4*)(&Mlds[h * 260 + dd * 16 + f4 * 4]);
        float vd = v[dd];
        ax += vd * m4.x; ay += vd * m4.y; az += vd * m4.z; aw += vd * m4.w;
      }
      atomicAdd(hb + f4 * 4 + 0, beta * ax);
      atomicAdd(hb + f4 * 4 + 1, beta * ay);
      atomicAdd(hb + f4 * 4 + 2, beta * az);
      atomicAdd(hb + f4 * 4 + 3, beta * aw);
    }
  }
}

// ---------------------------------------------------------------- output GEMM
__global__ __launch_bounds__(256) void k_out(
    const float* __restrict__ Hagg, const float* __restrict__ Wa,
    const float* __restrict__ ba,
    const float* __restrict__ x0, const float* __restrict__ x1,
    const float* __restrict__ x2, const float* __restrict__ skip,
    float* __restrict__ out, int N)
{
  __shared__ __attribute__((aligned(16))) unsigned short Wt[128 * 136];
  int m = blockIdx.y;
  const float* X = (m == 0) ? x0 : ((m == 1) ? x1 : x2);
  int tid = threadIdx.x;
  for (int idx = tid; idx < 128 * 128; idx += 256) {
    int k = idx >> 7, c = idx & 127;
    Wt[c * 136 + k] = f2bf(Wa[idx]);
  }
  __syncthreads();
  float alpha = 1.f / (1.f + __expf(-skip[0]));
  float oma = 1.f - alpha;
  int wave = tid >> 6, lane = tid & 63;
  int quad = lane >> 4, l16 = lane & 15;
  int row0 = blockIdx.x * 64 + wave * 16;
  int arow = row0 + l16; if (arow >= N) arow = N - 1;
  const float* hp = Hagg + (size_t)m * N * D + (size_t)arow * D;
  floatx4 acc[8];
#pragma unroll
  for (int ct = 0; ct < 8; ct++) acc[ct] = (floatx4)0.f;
#pragma unroll
  for (int kk = 0; kk < 128; kk += 32) {
    float4 f0 = *(const float4*)(hp + kk + quad * 8);
    float4 f1 = *(const float4*)(hp + kk + quad * 8 + 4);
    ushortx8 uu;
    uu[0]=f2bf(f0.x); uu[1]=f2bf(f0.y); uu[2]=f2bf(f0.z); uu[3]=f2bf(f0.w);
    uu[4]=f2bf(f1.x); uu[5]=f2bf(f1.y); uu[6]=f2bf(f1.z); uu[7]=f2bf(f1.w);
    bf16x8 af = __builtin_bit_cast(bf16x8, uu);
#pragma unroll
    for (int ct = 0; ct < 8; ct++) {
      uint4 bu = *(const uint4*)(&Wt[(ct * 16 + l16) * 136 + kk + quad * 8]);
      bf16x8 bf = __builtin_bit_cast(bf16x8, bu);
      acc[ct] = __builtin_amdgcn_mfma_f32_16x16x32_bf16(af, bf, acc[ct], 0, 0, 0);
    }
  }
  float* om = out + (size_t)m * N * D;
#pragma unroll
  for (int ct = 0; ct < 8; ct++) {
    int col = ct * 16 + l16;
    float bias = ba[col];
#pragma unroll
    for (int i = 0; i < 4; i++) {
      int r = row0 + quad * 4 + i;
      if (r < N) {
        om[(size_t)r * D + col] =
            (acc[ct][i] + bias) * alpha + X[(size_t)r * D + col] * oma;
      }
    }
  }
}

// ---------------------------------------------------------------- launch
extern "C" void kernel_launch(void* const* d_in, const int* in_sizes, int n_in,
                              void* d_out, int out_size, void* d_ws, size_t ws_size,
                              hipStream_t stream) {
  const float* x0 = (const float*)d_in[0];
  const float* x1 = (const float*)d_in[1];
  const float* x2 = (const float*)d_in[2];
  const float* Wk = (const float*)d_in[3];
  const float* bk = (const float*)d_in[4];
  const float* Wq = (const float*)d_in[5];
  const float* bq = (const float*)d_in[6];
  const float* Wv = (const float*)d_in[7];
  const float* bv = (const float*)d_in[8];
  const float* Wa = (const float*)d_in[9];
  const float* ba = (const float*)d_in[10];
  const float* rel_att = (const float*)d_in[11];
  const float* rel_msg = (const float*)d_in[12];
  const float* rel_pri = (const float*)d_in[13];
  const float* wm0 = (const float*)d_in[14];
  const float* wm1 = (const float*)d_in[15];
  const float* wm2 = (const float*)d_in[16];
  const float* skip = (const float*)d_in[17];
  const int* src = (const int*)d_in[18];
  const int* dstv = (const int*)d_in[19];
  int N = in_sizes[0] / D;      // 20000
  int E = in_sizes[18];         // 160000

  char* wsb = (char*)d_ws;
  unsigned short* P = (unsigned short*)wsb;              // 9*N*128 bf16
  size_t P_bytes = (size_t)9 * N * D * sizeof(unsigned short);
  float* att_ws = (float*)(wsb + P_bytes);               // 3*E*8
  float* lam_ws = att_ws + (size_t)3 * E * NH;           // 3*E*8
  float* t_ws   = lam_ws + (size_t)3 * E * NH;           // E*8
  float* sumA   = t_ws   + (size_t)E * NH;               // 3*N*8  (zeroed)
  float* sumAl  = sumA   + (size_t)3 * N * NH;           // N*8    (zeroed)
  float* sumT   = sumAl  + (size_t)N * NH;               // N*8    (zeroed)
  float* hagg   = sumT   + (size_t)N * NH;               // 3*N*128 (zeroed)
  long long zero_n = (long long)((size_t)5 * N * NH + (size_t)3 * N * D);

  k_zero<<<dim3(1024), 256, 0, stream>>>(sumA, zero_n);
  k_proj<<<dim3((N + 63) / 64, 9), 256, 0, stream>>>(
      x0, x1, x2, Wk, bk, Wq, bq, Wv, bv, P, N);
  int eb = (E * NH + 255) / 256;
  k_edge_att<<<dim3(eb), 256, 0, stream>>>(
      P, src, dstv, rel_att, rel_pri, wm0, wm1, wm2,
      att_ws, lam_ws, sumA, sumAl, N, E);
  k_edge_beta<<<dim3(eb), 256, 0, stream>>>(
      att_ws, lam_ws, sumA, sumAl, dstv, t_ws, sumT, N, E);
  k_edge_agg<<<dim3(eb), 256, 0, stream>>>(
      P, t_ws, sumT, src, dstv, rel_msg, hagg, N, E);
  k_out<<<dim3((N + 63) / 64, 3), 256, 0, stream>>>(
      hagg, Wa, ba, x0, x1, x2, skip, (float*)d_out, N);
}

// Round 3
// 349.129 us; speedup vs baseline: 10.5364x; 10.5364x over previous
//
#include <hip/hip_runtime.h>

#define D 128
#define NH 8

typedef __bf16 bf16x8 __attribute__((ext_vector_type(8)));
typedef unsigned short ushortx8 __attribute__((ext_vector_type(8)));
typedef float floatx4 __attribute__((ext_vector_type(4)));

__device__ __forceinline__ float bf2f(unsigned short u) {
  union { unsigned int i; float f; } x; x.i = ((unsigned int)u) << 16; return x.f;
}
__device__ __forceinline__ unsigned short f2bf(float f) {
  union { float f; unsigned int i; } x; x.f = f;
  unsigned int i = x.i;
  return (unsigned short)((i + 0x7FFFu + ((i >> 16) & 1u)) >> 16);
}

// ---------------------------------------------------------------- zero init
__global__ void k_zero(float* __restrict__ p, long long n) {
  long long i = ((long long)blockIdx.x * blockDim.x + threadIdx.x) * 4;
  long long stride = (long long)gridDim.x * blockDim.x * 4;
  for (; i + 3 < n; i += stride) {
    *(float4*)(p + i) = make_float4(0.f, 0.f, 0.f, 0.f);
  }
}

// ---------------------------------------------------------------- weight fold
// Produces 6 transposed bf16 weight planes Wt_all[p][c*128+k] and fp32 biases:
// p0: Wk           p1: Wq folded with rel_att      p2..4: Wq folded with wm_m
// p5: Wv folded with rel_msg
__global__ __launch_bounds__(256) void k_transform(
    const float* __restrict__ Wk, const float* __restrict__ bk,
    const float* __restrict__ Wq, const float* __restrict__ bq,
    const float* __restrict__ Wv, const float* __restrict__ bv,
    const float* __restrict__ rel_att, const float* __restrict__ rel_msg,
    const float* __restrict__ wm0, const float* __restrict__ wm1,
    const float* __restrict__ wm2,
    unsigned short* __restrict__ Wt_all, float* __restrict__ bias_all)
{
  int gid = blockIdx.x * 256 + threadIdx.x;
  if (gid >= 6 * 128 * 128) return;
  int p = gid >> 14;
  int idx = gid & 16383;
  int c = idx >> 7, k = idx & 127;
  int h = c >> 4, r = c & 15;     // r = d for p1..4, r = f for p5
  float wsum = 0.f, bsum = 0.f;
  if (p == 0) {
    wsum = Wk[k * 128 + c];
    bsum = bk[c];
  } else if (p <= 4) {
    const float* M = (p == 1) ? rel_att : ((p == 2) ? wm0 : ((p == 3) ? wm1 : wm2));
    // out[c=h*16+d][k] = sum_f Wq[k][h*16+f] * M[h][d][f]
#pragma unroll
    for (int f = 0; f < 16; f++) {
      float mv = M[h * 256 + r * 16 + f];
      wsum += Wq[k * 128 + h * 16 + f] * mv;
      bsum += bq[h * 16 + f] * mv;
    }
  } else {
    // out[c=h*16+f][k] = sum_d Wv[k][h*16+d] * rel_msg[h][d][f]
#pragma unroll
    for (int d = 0; d < 16; d++) {
      float mv = rel_msg[h * 256 + d * 16 + r];
      wsum += Wv[k * 128 + h * 16 + d] * mv;
      bsum += bv[h * 16 + d] * mv;
    }
  }
  Wt_all[(size_t)p * 16384 + c * 128 + k] = f2bf(wsum);
  if (k == 0) bias_all[p * 128 + c] = bsum;
}

// ---------------------------------------------------------------- projections
// P[plane][N][128] bf16, plane = pt*3+m: pt 0=K, 1=QA, 2=QW_m, 3=VM.
__global__ __launch_bounds__(256) void k_proj(
    const float* __restrict__ x0, const float* __restrict__ x1,
    const float* __restrict__ x2,
    const unsigned short* __restrict__ Wt_all, const float* __restrict__ bias_all,
    unsigned short* __restrict__ P, int N)
{
  __shared__ __attribute__((aligned(16))) unsigned short Wt[128 * 136];
  int combo = blockIdx.y;
  int m = combo % 3, pt = combo / 3;
  int wp = (pt == 0) ? 0 : ((pt == 1) ? 1 : ((pt == 2) ? (2 + m) : 5));
  const float* X = (m == 0) ? x0 : ((m == 1) ? x1 : x2);
  const unsigned short* Wsrc = Wt_all + (size_t)wp * 16384;
  const float* B = bias_all + wp * 128;
  int tid = threadIdx.x;
  for (int idx = tid; idx < 128 * 128; idx += 256) {
    int c = idx >> 7, k = idx & 127;
    Wt[c * 136 + k] = Wsrc[idx];
  }
  __syncthreads();
  int wave = tid >> 6, lane = tid & 63;
  int quad = lane >> 4, l16 = lane & 15;
  int row0 = blockIdx.x * 64 + wave * 16;
  int arow = row0 + l16; if (arow >= N) arow = N - 1;
  const float* ap = X + (size_t)arow * D;
  floatx4 acc[8];
#pragma unroll
  for (int ct = 0; ct < 8; ct++) acc[ct] = (floatx4)0.f;
#pragma unroll
  for (int kk = 0; kk < 128; kk += 32) {
    float4 f0 = *(const float4*)(ap + kk + quad * 8);
    float4 f1 = *(const float4*)(ap + kk + quad * 8 + 4);
    ushortx8 uu;
    uu[0]=f2bf(f0.x); uu[1]=f2bf(f0.y); uu[2]=f2bf(f0.z); uu[3]=f2bf(f0.w);
    uu[4]=f2bf(f1.x); uu[5]=f2bf(f1.y); uu[6]=f2bf(f1.z); uu[7]=f2bf(f1.w);
    bf16x8 af = __builtin_bit_cast(bf16x8, uu);
#pragma unroll
    for (int ct = 0; ct < 8; ct++) {
      uint4 bu = *(const uint4*)(&Wt[(ct * 16 + l16) * 136 + kk + quad * 8]);
      bf16x8 bf = __builtin_bit_cast(bf16x8, bu);
      acc[ct] = __builtin_amdgcn_mfma_f32_16x16x32_bf16(af, bf, acc[ct], 0, 0, 0);
    }
  }
  unsigned short* Pout = P + (size_t)combo * N * D;
#pragma unroll
  for (int ct = 0; ct < 8; ct++) {
    int col = ct * 16 + l16;
    float bias = B[col];
#pragma unroll
    for (int i = 0; i < 4; i++) {
      int r = row0 + quad * 4 + i;
      if (r < N) Pout[(size_t)r * D + col] = f2bf(acc[ct][i] + bias);
    }
  }
}

// ---------------------------------------------------------------- edge att+lam
// thread = (e,h): att[m] = dot16(k[m][src], qa[m][dst]) * pri ;
//                 lam    = softmax_m dot16(k[m][src], qw_m[m][dst])
__global__ __launch_bounds__(256) void k_edge_att(
    const unsigned short* __restrict__ P, const int* __restrict__ src,
    const int* __restrict__ dst, const float* __restrict__ rel_pri,
    float* __restrict__ att_ws, float* __restrict__ lam_ws, int N, int E)
{
  int gid = blockIdx.x * 256 + threadIdx.x;
  int e = gid >> 3, h = gid & 7;
  if (e >= E) return;
  int s = src[e], d = dst[e];
  float pri = rel_pri[h] * 2.5f;   // rel_pri / sqrt(16) * 10
  float attv[3], lamv[3];
#pragma unroll
  for (int m = 0; m < 3; m++) {
    const unsigned short* kp  = P + ((size_t)m * N + s) * D + h * 16;
    const unsigned short* qap = P + ((size_t)(3 + m) * N + d) * D + h * 16;
    const unsigned short* qwp = P + ((size_t)(6 + m) * N + d) * D + h * 16;
    union { uint4 u; unsigned short us[8]; } k0, k1, a0, a1, w0, w1;
    k0.u = *(const uint4*)kp;  k1.u = *(const uint4*)(kp + 8);
    a0.u = *(const uint4*)qap; a1.u = *(const uint4*)(qap + 8);
    w0.u = *(const uint4*)qwp; w1.u = *(const uint4*)(qwp + 8);
    float da = 0.f, dw = 0.f;
#pragma unroll
    for (int j = 0; j < 8; j++) {
      float klo = bf2f(k0.us[j]), khi = bf2f(k1.us[j]);
      da += klo * bf2f(a0.us[j]) + khi * bf2f(a1.us[j]);
      dw += klo * bf2f(w0.us[j]) + khi * bf2f(w1.us[j]);
    }
    attv[m] = da * pri;
    lamv[m] = dw;
  }
  size_t E8 = (size_t)E * 8;
  size_t eh = (size_t)e * 8 + h;
  att_ws[eh] = attv[0]; att_ws[E8 + eh] = attv[1]; att_ws[2 * E8 + eh] = attv[2];
  float mx = fmaxf(lamv[0], fmaxf(lamv[1], lamv[2]));
  float e0 = __expf(lamv[0] - mx), e1 = __expf(lamv[1] - mx), e2 = __expf(lamv[2] - mx);
  float inv = 1.f / (e0 + e1 + e2);
  lam_ws[eh] = e0 * inv; lam_ws[E8 + eh] = e1 * inv; lam_ws[2 * E8 + eh] = e2 * inv;
}

// ---------------------------------------------------------------- CSR build
__global__ void k_hist(const int* __restrict__ dst, int* __restrict__ counts, int E) {
  int e = blockIdx.x * 256 + threadIdx.x;
  if (e < E) atomicAdd(&counts[dst[e]], 1);
}

__global__ __launch_bounds__(1024) void k_scan(
    const int* __restrict__ counts, int* __restrict__ row_start, int N) {
  __shared__ int buf[1024];
  __shared__ int carry;
  int tid = threadIdx.x;
  if (tid == 0) carry = 0;
  __syncthreads();
  for (int base = 0; base < N; base += 1024) {
    int v = (base + tid < N) ? counts[base + tid] : 0;
    buf[tid] = v;
    __syncthreads();
    for (int off = 1; off < 1024; off <<= 1) {
      int add = (tid >= off) ? buf[tid - off] : 0;
      __syncthreads();
      buf[tid] += add;
      __syncthreads();
    }
    if (base + tid < N) row_start[base + tid] = carry + buf[tid] - v;
    int total = buf[1023];
    __syncthreads();
    if (tid == 0) carry += total;
    __syncthreads();
  }
  if (tid == 0) row_start[N] = carry;
}

__global__ void k_scatter(const int* __restrict__ dst, const int* __restrict__ row_start,
                          int* __restrict__ cursor, int* __restrict__ eidx, int E) {
  int e = blockIdx.x * 256 + threadIdx.x;
  if (e < E) {
    int d = dst[e];
    int pos = atomicAdd(&cursor[d], 1);
    eidx[row_start[d] + pos] = e;
  }
}

// ---------------------------------------------------------------- node kernel
// One wave per dst node: segment softmaxes in registers (shfl reductions),
// then feature-parallel aggregation of beta * vmsg. No global atomics.
__global__ __launch_bounds__(256) void k_node(
    const unsigned short* __restrict__ P,
    const float* __restrict__ att_ws, const float* __restrict__ lam_ws,
    const int* __restrict__ row_start, const int* __restrict__ eidx,
    const int* __restrict__ src,
    float* __restrict__ hagg, int N, int E)
{
  int tid = threadIdx.x;
  int wave = tid >> 6, lane = tid & 63;
  int n = blockIdx.x * 4 + wave;
  if (n >= N) return;
  int ro = row_start[n];
  int deg = row_start[n + 1] - ro;
  float acc00 = 0, acc01 = 0, acc10 = 0, acc11 = 0, acc20 = 0, acc21 = 0;
  if (deg > 0) {
    int h = lane & 7, slot = lane >> 3;
    size_t E8 = (size_t)E * 8;
    const unsigned int* Pu = (const unsigned int*)P;
    // ---- phase 1: sumA[m], sumAl
    float sA0 = 0, sA1 = 0, sA2 = 0, sAl = 0;
    for (int base = 0; base < deg; base += 8) {
      int idx = base + slot;
      if (idx < deg) {
        int e = eidx[ro + idx];
        size_t eh = (size_t)e * 8 + h;
        float a0 = att_ws[eh], a1 = att_ws[E8 + eh], a2 = att_ws[2 * E8 + eh];
        float align = -(fabsf(a0 - a1) + fabsf(a0 - a2) + fabsf(a1 - a2)) * (1.f / 3.f);
        sA0 += __expf(a0); sA1 += __expf(a1); sA2 += __expf(a2);
        sAl += __expf(align);
      }
    }
#pragma unroll
    for (int off = 8; off < 64; off <<= 1) {
      sA0 += __shfl_xor(sA0, off, 64);
      sA1 += __shfl_xor(sA1, off, 64);
      sA2 += __shfl_xor(sA2, off, 64);
      sAl += __shfl_xor(sAl, off, 64);
    }
    float rA0 = 1.f / fmaxf(sA0, 1e-30f), rA1 = 1.f / fmaxf(sA1, 1e-30f);
    float rA2 = 1.f / fmaxf(sA2, 1e-30f), rAl = 1.f / fmaxf(sAl, 1e-30f);
    // ---- phase 2: sumT
    float sT = 0;
    for (int base = 0; base < deg; base += 8) {
      int idx = base + slot;
      if (idx < deg) {
        int e = eidx[ro + idx];
        size_t eh = (size_t)e * 8 + h;
        float a0 = att_ws[eh], a1 = att_ws[E8 + eh], a2 = att_ws[2 * E8 + eh];
        float l0 = lam_ws[eh], l1 = lam_ws[E8 + eh], l2 = lam_ws[2 * E8 + eh];
        float align = -(fabsf(a0 - a1) + fabsf(a0 - a2) + fabsf(a1 - a2)) * (1.f / 3.f);
        float t = (l0 * __expf(a0) * rA0 + l1 * __expf(a1) * rA1 + l2 * __expf(a2) * rA2)
                  * (__expf(align) * rAl);
        sT += __expf(t);
      }
    }
#pragma unroll
    for (int off = 8; off < 64; off <<= 1) sT += __shfl_xor(sT, off, 64);
    float rT = 1.f / fmaxf(sT, 1e-30f);
    // ---- phase 3: beta + aggregation
    for (int base = 0; base < deg; base += 8) {
      int idx = base + slot;
      float beta = 0.f; int sv = 0;
      if (idx < deg) {
        int e = eidx[ro + idx];
        size_t eh = (size_t)e * 8 + h;
        float a0 = att_ws[eh], a1 = att_ws[E8 + eh], a2 = att_ws[2 * E8 + eh];
        float l0 = lam_ws[eh], l1 = lam_ws[E8 + eh], l2 = lam_ws[2 * E8 + eh];
        float align = -(fabsf(a0 - a1) + fabsf(a0 - a2) + fabsf(a1 - a2)) * (1.f / 3.f);
        float t = (l0 * __expf(a0) * rA0 + l1 * __expf(a1) * rA1 + l2 * __expf(a2) * rA2)
                  * (__expf(align) * rAl);
        beta = __expf(t) * rT;
        sv = src[e];
      }
      int jmax = min(8, deg - base);
      int hagg_lane = lane >> 3;
      for (int jj = 0; jj < jmax; jj++) {
        float b = __shfl(beta, jj * 8 + hagg_lane, 64);
        int s = __shfl(sv, jj * 8, 64);
        unsigned int u0 = Pu[((size_t)9 * N + s) * 64 + lane];
        unsigned int u1 = Pu[((size_t)10 * N + s) * 64 + lane];
        unsigned int u2 = Pu[((size_t)11 * N + s) * 64 + lane];
        acc00 += b * bf2f((unsigned short)u0); acc01 += b * bf2f((unsigned short)(u0 >> 16));
        acc10 += b * bf2f((unsigned short)u1); acc11 += b * bf2f((unsigned short)(u1 >> 16));
        acc20 += b * bf2f((unsigned short)u2); acc21 += b * bf2f((unsigned short)(u2 >> 16));
      }
    }
  }
  float2* o0 = (float2*)(hagg + ((size_t)0 * N + n) * D) + lane;
  float2* o1 = (float2*)(hagg + ((size_t)1 * N + n) * D) + lane;
  float2* o2 = (float2*)(hagg + ((size_t)2 * N + n) * D) + lane;
  *o0 = make_float2(acc00, acc01);
  *o1 = make_float2(acc10, acc11);
  *o2 = make_float2(acc20, acc21);
}

// ---------------------------------------------------------------- output GEMM
__global__ __launch_bounds__(256) void k_out(
    const float* __restrict__ Hagg, const float* __restrict__ Wa,
    const float* __restrict__ ba,
    const float* __restrict__ x0, const float* __restrict__ x1,
    const float* __restrict__ x2, const float* __restrict__ skip,
    float* __restrict__ out, int N)
{
  __shared__ __attribute__((aligned(16))) unsigned short Wt[128 * 136];
  int m = blockIdx.y;
  const float* X = (m == 0) ? x0 : ((m == 1) ? x1 : x2);
  int tid = threadIdx.x;
  for (int idx = tid; idx < 128 * 128; idx += 256) {
    int k = idx >> 7, c = idx & 127;
    Wt[c * 136 + k] = f2bf(Wa[idx]);
  }
  __syncthreads();
  float alpha = 1.f / (1.f + __expf(-skip[0]));
  float oma = 1.f - alpha;
  int wave = tid >> 6, lane = tid & 63;
  int quad = lane >> 4, l16 = lane & 15;
  int row0 = blockIdx.x * 64 + wave * 16;
  int arow = row0 + l16; if (arow >= N) arow = N - 1;
  const float* hp = Hagg + (size_t)m * N * D + (size_t)arow * D;
  floatx4 acc[8];
#pragma unroll
  for (int ct = 0; ct < 8; ct++) acc[ct] = (floatx4)0.f;
#pragma unroll
  for (int kk = 0; kk < 128; kk += 32) {
    float4 f0 = *(const float4*)(hp + kk + quad * 8);
    float4 f1 = *(const float4*)(hp + kk + quad * 8 + 4);
    ushortx8 uu;
    uu[0]=f2bf(f0.x); uu[1]=f2bf(f0.y); uu[2]=f2bf(f0.z); uu[3]=f2bf(f0.w);
    uu[4]=f2bf(f1.x); uu[5]=f2bf(f1.y); uu[6]=f2bf(f1.z); uu[7]=f2bf(f1.w);
    bf16x8 af = __builtin_bit_cast(bf16x8, uu);
#pragma unroll
    for (int ct = 0; ct < 8; ct++) {
      uint4 bu = *(const uint4*)(&Wt[(ct * 16 + l16) * 136 + kk + quad * 8]);
      bf16x8 bf = __builtin_bit_cast(bf16x8, bu);
      acc[ct] = __builtin_amdgcn_mfma_f32_16x16x32_bf16(af, bf, acc[ct], 0, 0, 0);
    }
  }
  float* om = out + (size_t)m * N * D;
#pragma unroll
  for (int ct = 0; ct < 8; ct++) {
    int col = ct * 16 + l16;
    float bias = ba[col];
#pragma unroll
    for (int i = 0; i < 4; i++) {
      int r = row0 + quad * 4 + i;
      if (r < N) {
        om[(size_t)r * D + col] =
            (acc[ct][i] + bias) * alpha + X[(size_t)r * D + col] * oma;
      }
    }
  }
}

// ---------------------------------------------------------------- launch
extern "C" void kernel_launch(void* const* d_in, const int* in_sizes, int n_in,
                              void* d_out, int out_size, void* d_ws, size_t ws_size,
                              hipStream_t stream) {
  const float* x0 = (const float*)d_in[0];
  const float* x1 = (const float*)d_in[1];
  const float* x2 = (const float*)d_in[2];
  const float* Wk = (const float*)d_in[3];
  const float* bk = (const float*)d_in[4];
  const float* Wq = (const float*)d_in[5];
  const float* bq = (const float*)d_in[6];
  const float* Wv = (const float*)d_in[7];
  const float* bv = (const float*)d_in[8];
  const float* Wa = (const float*)d_in[9];
  const float* ba = (const float*)d_in[10];
  const float* rel_att = (const float*)d_in[11];
  const float* rel_msg = (const float*)d_in[12];
  const float* rel_pri = (const float*)d_in[13];
  const float* wm0 = (const float*)d_in[14];
  const float* wm1 = (const float*)d_in[15];
  const float* wm2 = (const float*)d_in[16];
  const float* skip = (const float*)d_in[17];
  const int* src = (const int*)d_in[18];
  const int* dstv = (const int*)d_in[19];
  int N = in_sizes[0] / D;      // 20000
  int E = in_sizes[18];         // 160000

  char* wsb = (char*)d_ws;
  size_t off = 0;
  auto alloc = [&](size_t bytes) { size_t o = off; off += (bytes + 63) & ~(size_t)63; return o; };
  unsigned short* P       = (unsigned short*)(wsb + alloc((size_t)12 * N * D * 2));
  unsigned short* Wt_all  = (unsigned short*)(wsb + alloc((size_t)6 * 16384 * 2));
  float*          bias_all= (float*)(wsb + alloc((size_t)6 * 128 * 4));
  float*          att_ws  = (float*)(wsb + alloc((size_t)3 * E * NH * 4));
  float*          lam_ws  = (float*)(wsb + alloc((size_t)3 * E * NH * 4));
  int*            counts  = (int*)(wsb + alloc((size_t)N * 4));
  int*            cursor  = (int*)(wsb + alloc((size_t)N * 4));
  int*            row_start = (int*)(wsb + alloc((size_t)(N + 1) * 4));
  int*            eidx    = (int*)(wsb + alloc((size_t)E * 4));
  float*          hagg    = (float*)(wsb + alloc((size_t)3 * N * D * 4));

  // zero counts + cursor (contiguous allocations, but zero separately for safety)
  k_zero<<<dim3(20), 256, 0, stream>>>((float*)counts, N);
  k_zero<<<dim3(20), 256, 0, stream>>>((float*)cursor, N);

  k_transform<<<dim3(384), 256, 0, stream>>>(
      Wk, bk, Wq, bq, Wv, bv, rel_att, rel_msg, wm0, wm1, wm2, Wt_all, bias_all);
  k_proj<<<dim3((N + 63) / 64, 12), 256, 0, stream>>>(
      x0, x1, x2, Wt_all, bias_all, P, N);
  k_edge_att<<<dim3((E * NH + 255) / 256), 256, 0, stream>>>(
      P, src, dstv, rel_pri, att_ws, lam_ws, N, E);
  k_hist<<<dim3((E + 255) / 256), 256, 0, stream>>>(dstv, counts, E);
  k_scan<<<dim3(1), 1024, 0, stream>>>(counts, row_start, N);
  k_scatter<<<dim3((E + 255) / 256), 256, 0, stream>>>(dstv, row_start, cursor, eidx, E);
  k_node<<<dim3((N + 3) / 4), 256, 0, stream>>>(
      P, att_ws, lam_ws, row_start, eidx, src, hagg, N, E);
  k_out<<<dim3((N + 63) / 64, 3), 256, 0, stream>>>(
      hagg, Wa, ba, x0, x1, x2, skip, (float*)d_out, N);
}

// Round 4
// 305.472 us; speedup vs baseline: 12.0422x; 1.1429x over previous
//
#include <hip/hip_runtime.h>

#define D 128
#define NH 8

typedef __bf16 bf16x8 __attribute__((ext_vector_type(8)));
typedef unsigned short ushortx8 __attribute__((ext_vector_type(8)));
typedef float floatx4 __attribute__((ext_vector_type(4)));

__device__ __forceinline__ float bf2f(unsigned short u) {
  union { unsigned int i; float f; } x; x.i = ((unsigned int)u) << 16; return x.f;
}
__device__ __forceinline__ unsigned short f2bf(float f) {
  union { float f; unsigned int i; } x; x.f = f;
  unsigned int i = x.i;
  return (unsigned short)((i + 0x7FFFu + ((i >> 16) & 1u)) >> 16);
}
// accumulate both bf16 halves of packed uints into s
__device__ __forceinline__ void acc2(unsigned int ku, unsigned int qu, float& s) {
  union { unsigned int i; float f; } a, b;
  a.i = ku << 16;          b.i = qu << 16;          s += a.f * b.f;
  a.i = ku & 0xffff0000u;  b.i = qu & 0xffff0000u;  s += a.f * b.f;
}

// ---------------------------------------------------------------- zero init
__global__ void k_zero(float* __restrict__ p, long long n) {
  long long i = ((long long)blockIdx.x * blockDim.x + threadIdx.x) * 4;
  long long stride = (long long)gridDim.x * blockDim.x * 4;
  for (; i + 3 < n; i += stride) {
    *(float4*)(p + i) = make_float4(0.f, 0.f, 0.f, 0.f);
  }
}

// ---------------------------------------------------------------- weight fold
// p0: Wk ; p1: Wq·rel_attT scaled by rel_pri*2.5 ; p2..4: Wq·wm_mT ; p5: Wv·rel_msg
__global__ __launch_bounds__(256) void k_transform(
    const float* __restrict__ Wk, const float* __restrict__ bk,
    const float* __restrict__ Wq, const float* __restrict__ bq,
    const float* __restrict__ Wv, const float* __restrict__ bv,
    const float* __restrict__ rel_att, const float* __restrict__ rel_msg,
    const float* __restrict__ rel_pri,
    const float* __restrict__ wm0, const float* __restrict__ wm1,
    const float* __restrict__ wm2,
    unsigned short* __restrict__ Wt_all, float* __restrict__ bias_all)
{
  int gid = blockIdx.x * 256 + threadIdx.x;
  if (gid >= 6 * 128 * 128) return;
  int p = gid >> 14;
  int idx = gid & 16383;
  int c = idx >> 7, k = idx & 127;
  int h = c >> 4, r = c & 15;
  float wsum = 0.f, bsum = 0.f;
  if (p == 0) {
    wsum = Wk[k * 128 + c];
    bsum = bk[c];
  } else if (p <= 4) {
    const float* M = (p == 1) ? rel_att : ((p == 2) ? wm0 : ((p == 3) ? wm1 : wm2));
#pragma unroll
    for (int f = 0; f < 16; f++) {
      float mv = M[h * 256 + r * 16 + f];
      wsum += Wq[k * 128 + h * 16 + f] * mv;
      bsum += bq[h * 16 + f] * mv;
    }
    if (p == 1) { float sc = rel_pri[h] * 2.5f; wsum *= sc; bsum *= sc; }
  } else {
#pragma unroll
    for (int d = 0; d < 16; d++) {
      float mv = rel_msg[h * 256 + d * 16 + r];
      wsum += Wv[k * 128 + h * 16 + d] * mv;
      bsum += bv[h * 16 + d] * mv;
    }
  }
  Wt_all[(size_t)p * 16384 + c * 128 + k] = f2bf(wsum);
  if (k == 0) bias_all[p * 128 + c] = bsum;
}

// ---------------------------------------------------------------- projections
// P[plane][N][128] bf16, plane = pt*3+m: pt 0=K, 1=QA(pri-scaled), 2=QW_m, 3=VM.
__global__ __launch_bounds__(256) void k_proj(
    const float* __restrict__ x0, const float* __restrict__ x1,
    const float* __restrict__ x2,
    const unsigned short* __restrict__ Wt_all, const float* __restrict__ bias_all,
    unsigned short* __restrict__ P, int N)
{
  __shared__ __attribute__((aligned(16))) unsigned short Wt[128 * 136];
  int combo = blockIdx.y;
  int m = combo % 3, pt = combo / 3;
  int wp = (pt == 0) ? 0 : ((pt == 1) ? 1 : ((pt == 2) ? (2 + m) : 5));
  const float* X = (m == 0) ? x0 : ((m == 1) ? x1 : x2);
  const unsigned short* Wsrc = Wt_all + (size_t)wp * 16384;
  const float* B = bias_all + wp * 128;
  int tid = threadIdx.x;
  for (int idx = tid; idx < 128 * 128; idx += 256) {
    int c = idx >> 7, k = idx & 127;
    Wt[c * 136 + k] = Wsrc[idx];
  }
  __syncthreads();
  int wave = tid >> 6, lane = tid & 63;
  int quad = lane >> 4, l16 = lane & 15;
  int row0 = blockIdx.x * 64 + wave * 16;
  int arow = row0 + l16; if (arow >= N) arow = N - 1;
  const float* ap = X + (size_t)arow * D;
  floatx4 acc[8];
#pragma unroll
  for (int ct = 0; ct < 8; ct++) acc[ct] = (floatx4)0.f;
#pragma unroll
  for (int kk = 0; kk < 128; kk += 32) {
    float4 f0 = *(const float4*)(ap + kk + quad * 8);
    float4 f1 = *(const float4*)(ap + kk + quad * 8 + 4);
    ushortx8 uu;
    uu[0]=f2bf(f0.x); uu[1]=f2bf(f0.y); uu[2]=f2bf(f0.z); uu[3]=f2bf(f0.w);
    uu[4]=f2bf(f1.x); uu[5]=f2bf(f1.y); uu[6]=f2bf(f1.z); uu[7]=f2bf(f1.w);
    bf16x8 af = __builtin_bit_cast(bf16x8, uu);
#pragma unroll
    for (int ct = 0; ct < 8; ct++) {
      uint4 bu = *(const uint4*)(&Wt[(ct * 16 + l16) * 136 + kk + quad * 8]);
      bf16x8 bf = __builtin_bit_cast(bf16x8, bu);
      acc[ct] = __builtin_amdgcn_mfma_f32_16x16x32_bf16(af, bf, acc[ct], 0, 0, 0);
    }
  }
  unsigned short* Pout = P + (size_t)combo * N * D;
#pragma unroll
  for (int ct = 0; ct < 8; ct++) {
    int col = ct * 16 + l16;
    float bias = B[col];
#pragma unroll
    for (int i = 0; i < 4; i++) {
      int r = row0 + quad * 4 + i;
      if (r < N) Pout[(size_t)r * D + col] = f2bf(acc[ct][i] + bias);
    }
  }
}

// ---------------------------------------------------------------- CSR build
__global__ void k_hist(const int* __restrict__ dst, int* __restrict__ counts, int E) {
  int e = blockIdx.x * 256 + threadIdx.x;
  if (e < E) atomicAdd(&counts[dst[e]], 1);
}

// hierarchical exclusive scan: per-block shfl scan + partials
__global__ __launch_bounds__(1024) void k_scan_part(
    const int* __restrict__ counts, int* __restrict__ row_start,
    int* __restrict__ partials, int N)
{
  __shared__ int wsum[16];
  int tid = threadIdx.x;
  int gi = blockIdx.x * 1024 + tid;
  int v = (gi < N) ? counts[gi] : 0;
  int lane = tid & 63, wid = tid >> 6;
  int x = v;
#pragma unroll
  for (int off = 1; off < 64; off <<= 1) {
    int y = __shfl_up(x, off, 64);
    if (lane >= off) x += y;
  }
  if (lane == 63) wsum[wid] = x;
  __syncthreads();
  if (wid == 0) {
    int ws = (lane < 16) ? wsum[lane] : 0;
#pragma unroll
    for (int off = 1; off < 16; off <<= 1) {
      int y = __shfl_up(ws, off, 64);
      if (lane >= off) ws += y;
    }
    if (lane < 16) wsum[lane] = ws;
  }
  __syncthreads();
  int excl = x - v + (wid > 0 ? wsum[wid - 1] : 0);
  if (gi <= N) row_start[gi] = excl;
  if (tid == 0) partials[blockIdx.x] = wsum[15];
}

__global__ __launch_bounds__(1024) void k_scan_fix(
    int* __restrict__ row_start, const int* __restrict__ partials, int N, int nb)
{
  __shared__ int offs[64];
  int tid = threadIdx.x;
  if (tid == 0) {
    int acc = 0;
    for (int b = 0; b < nb; b++) { offs[b] = acc; acc += partials[b]; }
  }
  __syncthreads();
  for (int i = tid; i <= N; i += 1024) row_start[i] += offs[i >> 10];
}

__global__ void k_scatter(const int* __restrict__ dst, const int* __restrict__ row_start,
                          int* __restrict__ cursor, int* __restrict__ eidx, int E) {
  int e = blockIdx.x * 256 + threadIdx.x;
  if (e < E) {
    int d = dst[e];
    int pos = atomicAdd(&cursor[d], 1);
    eidx[row_start[d] + pos] = e;
  }
}

// ---------------------------------------------------------------- fused node kernel
// One wave per dst node. q-planes cached in registers; per-edge k gathered once;
// softmax state cached per chunk (deg<=64 fast path). No global atomics.
__device__ __forceinline__ void edge_vals(
    const unsigned short* __restrict__ P, size_t Nsz, int s, int h,
    const uint4 (&qa)[3][2], const uint4 (&qw)[3][2],
    float (&av)[3], float (&lv)[3])
{
#pragma unroll
  for (int m = 0; m < 3; m++) {
    const unsigned short* kp = P + ((size_t)m * Nsz + s) * 128 + h * 16;
    uint4 k0 = *(const uint4*)kp, k1 = *(const uint4*)(kp + 8);
    const unsigned int* ka = (const unsigned int*)&k0;
    const unsigned int* kb = (const unsigned int*)&k1;
    const unsigned int* a0 = (const unsigned int*)&qa[m][0];
    const unsigned int* a1 = (const unsigned int*)&qa[m][1];
    const unsigned int* w0 = (const unsigned int*)&qw[m][0];
    const unsigned int* w1 = (const unsigned int*)&qw[m][1];
    float da = 0.f, dw = 0.f;
#pragma unroll
    for (int j = 0; j < 4; j++) {
      acc2(ka[j], a0[j], da); acc2(kb[j], a1[j], da);
      acc2(ka[j], w0[j], dw); acc2(kb[j], w1[j], dw);
    }
    av[m] = da;          // rel_pri*2.5 already folded into QA plane
    lv[m] = dw;
  }
  float mx = fmaxf(lv[0], fmaxf(lv[1], lv[2]));
  float e0 = __expf(lv[0] - mx), e1 = __expf(lv[1] - mx), e2 = __expf(lv[2] - mx);
  float inv = 1.f / (e0 + e1 + e2);
  lv[0] = e0 * inv; lv[1] = e1 * inv; lv[2] = e2 * inv;
}

__global__ __launch_bounds__(256) void k_node(
    const unsigned short* __restrict__ P,
    const int* __restrict__ row_start, const int* __restrict__ eidx,
    const int* __restrict__ src,
    unsigned short* __restrict__ hagg, int N, int E)
{
  int tid = threadIdx.x;
  int wave = tid >> 6, lane = tid & 63;
  int n = blockIdx.x * 4 + wave;
  if (n >= N) return;
  int ro = row_start[n];
  int deg = row_start[n + 1] - ro;
  float acc00 = 0, acc01 = 0, acc10 = 0, acc11 = 0, acc20 = 0, acc21 = 0;
  if (deg > 0) {
    int h = lane & 7, slot = lane >> 3;
    size_t Nsz = (size_t)N;
    // cache q-slices (head h) for this node
    uint4 qa[3][2], qw[3][2];
#pragma unroll
    for (int m = 0; m < 3; m++) {
      const unsigned short* qap = P + ((size_t)(3 + m) * Nsz + n) * 128 + h * 16;
      const unsigned short* qwp = P + ((size_t)(6 + m) * Nsz + n) * 128 + h * 16;
      qa[m][0] = *(const uint4*)qap; qa[m][1] = *(const uint4*)(qap + 8);
      qw[m][0] = *(const uint4*)qwp; qw[m][1] = *(const uint4*)(qwp + 8);
    }
    int nch = (deg + 7) >> 3;
    // per-chunk caches (fast path: deg <= 64)
    float cX0[8], cX1[8], cX2[8], cEa[8], cT[8];
    int cS[8];
    // ---- phase 1: sumA_m, sumAl
    float sA0 = 0, sA1 = 0, sA2 = 0, sAl = 0;
#pragma unroll
    for (int c = 0; c < 8; c++) {
      int idx = c * 8 + slot;
      if (c < nch && idx < deg) {
        int e = eidx[ro + idx];
        int s = src[e]; cS[c] = s;
        float av[3], lv[3];
        edge_vals(P, Nsz, s, h, qa, qw, av, lv);
        float e0 = __expf(av[0]), e1 = __expf(av[1]), e2 = __expf(av[2]);
        float align = -(fabsf(av[0]-av[1]) + fabsf(av[0]-av[2]) + fabsf(av[1]-av[2])) * (1.f/3.f);
        float ea = __expf(align);
        cX0[c] = lv[0] * e0; cX1[c] = lv[1] * e1; cX2[c] = lv[2] * e2; cEa[c] = ea;
        sA0 += e0; sA1 += e1; sA2 += e2; sAl += ea;
      }
    }
    for (int c = 8; c < nch; c++) {          // rare deg>64 fallback
      int idx = c * 8 + slot;
      if (idx < deg) {
        int e = eidx[ro + idx]; int s = src[e];
        float av[3], lv[3];
        edge_vals(P, Nsz, s, h, qa, qw, av, lv);
        float align = -(fabsf(av[0]-av[1]) + fabsf(av[0]-av[2]) + fabsf(av[1]-av[2])) * (1.f/3.f);
        sA0 += __expf(av[0]); sA1 += __expf(av[1]); sA2 += __expf(av[2]);
        sAl += __expf(align);
      }
    }
#pragma unroll
    for (int off = 8; off < 64; off <<= 1) {
      sA0 += __shfl_xor(sA0, off, 64);
      sA1 += __shfl_xor(sA1, off, 64);
      sA2 += __shfl_xor(sA2, off, 64);
      sAl += __shfl_xor(sAl, off, 64);
    }
    float rA0 = 1.f / fmaxf(sA0, 1e-30f), rA1 = 1.f / fmaxf(sA1, 1e-30f);
    float rA2 = 1.f / fmaxf(sA2, 1e-30f), rAl = 1.f / fmaxf(sAl, 1e-30f);
    // ---- phase 2: sumT
    float sT = 0;
#pragma unroll
    for (int c = 0; c < 8; c++) {
      int idx = c * 8 + slot;
      if (c < nch && idx < deg) {
        float t = (cX0[c] * rA0 + cX1[c] * rA1 + cX2[c] * rA2) * (cEa[c] * rAl);
        cT[c] = t;
        sT += __expf(t);
      }
    }
    for (int c = 8; c < nch; c++) {
      int idx = c * 8 + slot;
      if (idx < deg) {
        int e = eidx[ro + idx]; int s = src[e];
        float av[3], lv[3];
        edge_vals(P, Nsz, s, h, qa, qw, av, lv);
        float align = -(fabsf(av[0]-av[1]) + fabsf(av[0]-av[2]) + fabsf(av[1]-av[2])) * (1.f/3.f);
        float t = (lv[0]*__expf(av[0])*rA0 + lv[1]*__expf(av[1])*rA1 + lv[2]*__expf(av[2])*rA2)
                  * (__expf(align) * rAl);
        sT += __expf(t);
      }
    }
#pragma unroll
    for (int off = 8; off < 64; off <<= 1) sT += __shfl_xor(sT, off, 64);
    float rT = 1.f / fmaxf(sT, 1e-30f);
    // ---- phase 3: beta + aggregation
    const unsigned int* Pu = (const unsigned int*)P;
    int hl = lane >> 3;
#pragma unroll
    for (int c = 0; c < 8; c++) {
      if (c < nch) {
        int idx = c * 8 + slot;
        float beta = 0.f; int sv = 0;
        if (idx < deg) { beta = __expf(cT[c]) * rT; sv = cS[c]; }
        int jmax = min(8, deg - c * 8);
        for (int jj = 0; jj < jmax; jj++) {
          float b = __shfl(beta, jj * 8 + hl, 64);
          int s = __shfl(sv, jj * 8, 64);
          unsigned int u0 = Pu[((size_t)9 * Nsz + s) * 64 + lane];
          unsigned int u1 = Pu[((size_t)10 * Nsz + s) * 64 + lane];
          unsigned int u2 = Pu[((size_t)11 * Nsz + s) * 64 + lane];
          acc00 += b * bf2f((unsigned short)u0); acc01 += b * bf2f((unsigned short)(u0 >> 16));
          acc10 += b * bf2f((unsigned short)u1); acc11 += b * bf2f((unsigned short)(u1 >> 16));
          acc20 += b * bf2f((unsigned short)u2); acc21 += b * bf2f((unsigned short)(u2 >> 16));
        }
      }
    }
    for (int c = 8; c < nch; c++) {
      int idx = c * 8 + slot;
      float beta = 0.f; int sv = 0;
      if (idx < deg) {
        int e = eidx[ro + idx]; sv = src[e];
        float av[3], lv[3];
        edge_vals(P, Nsz, sv, h, qa, qw, av, lv);
        float align = -(fabsf(av[0]-av[1]) + fabsf(av[0]-av[2]) + fabsf(av[1]-av[2])) * (1.f/3.f);
        float t = (lv[0]*__expf(av[0])*rA0 + lv[1]*__expf(av[1])*rA1 + lv[2]*__expf(av[2])*rA2)
                  * (__expf(align) * rAl);
        beta = __expf(t) * rT;
      }
      int jmax = min(8, deg - c * 8);
      for (int jj = 0; jj < jmax; jj++) {
        float b = __shfl(beta, jj * 8 + hl, 64);
        int s = __shfl(sv, jj * 8, 64);
        unsigned int u0 = Pu[((size_t)9 * Nsz + s) * 64 + lane];
        unsigned int u1 = Pu[((size_t)10 * Nsz + s) * 64 + lane];
        unsigned int u2 = Pu[((size_t)11 * Nsz + s) * 64 + lane];
        acc00 += b * bf2f((unsigned short)u0); acc01 += b * bf2f((unsigned short)(u0 >> 16));
        acc10 += b * bf2f((unsigned short)u1); acc11 += b * bf2f((unsigned short)(u1 >> 16));
        acc20 += b * bf2f((unsigned short)u2); acc21 += b * bf2f((unsigned short)(u2 >> 16));
      }
    }
  }
  unsigned int* ho = (unsigned int*)hagg;
  ho[((size_t)0 * N + n) * 64 + lane] = ((unsigned int)f2bf(acc01) << 16) | f2bf(acc00);
  ho[((size_t)1 * N + n) * 64 + lane] = ((unsigned int)f2bf(acc11) << 16) | f2bf(acc10);
  ho[((size_t)2 * N + n) * 64 + lane] = ((unsigned int)f2bf(acc21) << 16) | f2bf(acc20);
}

// ---------------------------------------------------------------- output GEMM
__global__ __launch_bounds__(256) void k_out(
    const unsigned short* __restrict__ Hagg, const float* __restrict__ Wa,
    const float* __restrict__ ba,
    const float* __restrict__ x0, const float* __restrict__ x1,
    const float* __restrict__ x2, const float* __restrict__ skip,
    float* __restrict__ out, int N)
{
  __shared__ __attribute__((aligned(16))) unsigned short Wt[128 * 136];
  int m = blockIdx.y;
  const float* X = (m == 0) ? x0 : ((m == 1) ? x1 : x2);
  int tid = threadIdx.x;
  for (int idx = tid; idx < 128 * 128; idx += 256) {
    int k = idx >> 7, c = idx & 127;
    Wt[c * 136 + k] = f2bf(Wa[idx]);
  }
  __syncthreads();
  float alpha = 1.f / (1.f + __expf(-skip[0]));
  float oma = 1.f - alpha;
  int wave = tid >> 6, lane = tid & 63;
  int quad = lane >> 4, l16 = lane & 15;
  int row0 = blockIdx.x * 64 + wave * 16;
  int arow = row0 + l16; if (arow >= N) arow = N - 1;
  const unsigned short* hp = Hagg + ((size_t)m * N + arow) * D;
  floatx4 acc[8];
#pragma unroll
  for (int ct = 0; ct < 8; ct++) acc[ct] = (floatx4)0.f;
#pragma unroll
  for (int kk = 0; kk < 128; kk += 32) {
    uint4 au = *(const uint4*)(hp + kk + quad * 8);
    bf16x8 af = __builtin_bit_cast(bf16x8, au);
#pragma unroll
    for (int ct = 0; ct < 8; ct++) {
      uint4 bu = *(const uint4*)(&Wt[(ct * 16 + l16) * 136 + kk + quad * 8]);
      bf16x8 bf = __builtin_bit_cast(bf16x8, bu);
      acc[ct] = __builtin_amdgcn_mfma_f32_16x16x32_bf16(af, bf, acc[ct], 0, 0, 0);
    }
  }
  float* om = out + (size_t)m * N * D;
#pragma unroll
  for (int ct = 0; ct < 8; ct++) {
    int col = ct * 16 + l16;
    float bias = ba[col];
#pragma unroll
    for (int i = 0; i < 4; i++) {
      int r = row0 + quad * 4 + i;
      if (r < N) {
        om[(size_t)r * D + col] =
            (acc[ct][i] + bias) * alpha + X[(size_t)r * D + col] * oma;
      }
    }
  }
}

// ---------------------------------------------------------------- launch
extern "C" void kernel_launch(void* const* d_in, const int* in_sizes, int n_in,
                              void* d_out, int out_size, void* d_ws, size_t ws_size,
                              hipStream_t stream) {
  const float* x0 = (const float*)d_in[0];
  const float* x1 = (const float*)d_in[1];
  const float* x2 = (const float*)d_in[2];
  const float* Wk = (const float*)d_in[3];
  const float* bk = (const float*)d_in[4];
  const float* Wq = (const float*)d_in[5];
  const float* bq = (const float*)d_in[6];
  const float* Wv = (const float*)d_in[7];
  const float* bv = (const float*)d_in[8];
  const float* Wa = (const float*)d_in[9];
  const float* ba = (const float*)d_in[10];
  const float* rel_att = (const float*)d_in[11];
  const float* rel_msg = (const float*)d_in[12];
  const float* rel_pri = (const float*)d_in[13];
  const float* wm0 = (const float*)d_in[14];
  const float* wm1 = (const float*)d_in[15];
  const float* wm2 = (const float*)d_in[16];
  const float* skip = (const float*)d_in[17];
  const int* src = (const int*)d_in[18];
  const int* dstv = (const int*)d_in[19];
  int N = in_sizes[0] / D;      // 20000
  int E = in_sizes[18];         // 160000

  char* wsb = (char*)d_ws;
  size_t off = 0;
  auto alloc = [&](size_t bytes) { size_t o = off; off += (bytes + 63) & ~(size_t)63; return o; };
  unsigned short* P        = (unsigned short*)(wsb + alloc((size_t)12 * N * D * 2));
  unsigned short* Wt_all   = (unsigned short*)(wsb + alloc((size_t)6 * 16384 * 2));
  float*          bias_all = (float*)(wsb + alloc((size_t)6 * 128 * 4));
  int*            cnt2     = (int*)(wsb + alloc((size_t)2 * N * 4));   // counts | cursor
  int*            row_start= (int*)(wsb + alloc((size_t)(N + 1) * 4));
  int*            eidx     = (int*)(wsb + alloc((size_t)E * 4));
  int*            partials = (int*)(wsb + alloc((size_t)64 * 4));
  unsigned short* hagg     = (unsigned short*)(wsb + alloc((size_t)3 * N * D * 2));
  int* counts = cnt2;
  int* cursor = cnt2 + N;

  k_zero<<<dim3(40), 256, 0, stream>>>((float*)cnt2, (long long)2 * N);
  k_transform<<<dim3(384), 256, 0, stream>>>(
      Wk, bk, Wq, bq, Wv, bv, rel_att, rel_msg, rel_pri, wm0, wm1, wm2, Wt_all, bias_all);
  k_proj<<<dim3((N + 63) / 64, 12), 256, 0, stream>>>(
      x0, x1, x2, Wt_all, bias_all, P, N);
  k_hist<<<dim3((E + 255) / 256), 256, 0, stream>>>(dstv, counts, E);
  int nb = (N + 1024) / 1024;
  k_scan_part<<<dim3(nb), 1024, 0, stream>>>(counts, row_start, partials, N);
  k_scan_fix<<<dim3(1), 1024, 0, stream>>>(row_start, partials, N, nb);
  k_scatter<<<dim3((E + 255) / 256), 256, 0, stream>>>(dstv, row_start, cursor, eidx, E);
  k_node<<<dim3((N + 3) / 4), 256, 0, stream>>>(
      P, row_start, eidx, src, hagg, N, E);
  k_out<<<dim3((N + 63) / 64, 3), 256, 0, stream>>>(
      hagg, Wa, ba, x0, x1, x2, skip, (float*)d_out, N);
}

// Round 5
// 280.939 us; speedup vs baseline: 13.0938x; 1.0873x over previous
//
#include <hip/hip_runtime.h>

#define D 128
#define NH 8

typedef __bf16 bf16x8 __attribute__((ext_vector_type(8)));
typedef unsigned short ushortx8 __attribute__((ext_vector_type(8)));
typedef float floatx4 __attribute__((ext_vector_type(4)));

__device__ __forceinline__ float bf2f(unsigned short u) {
  union { unsigned int i; float f; } x; x.i = ((unsigned int)u) << 16; return x.f;
}
__device__ __forceinline__ unsigned short f2bf(float f) {
  union { float f; unsigned int i; } x; x.f = f;
  unsigned int i = x.i;
  return (unsigned short)((i + 0x7FFFu + ((i >> 16) & 1u)) >> 16);
}
// accumulate both bf16 halves of packed uints into s
__device__ __forceinline__ void acc2(unsigned int ku, unsigned int qu, float& s) {
  union { unsigned int i; float f; } a, b;
  a.i = ku << 16;          b.i = qu << 16;          s += a.f * b.f;
  a.i = ku & 0xffff0000u;  b.i = qu & 0xffff0000u;  s += a.f * b.f;
}

// ---------------------------------------------------------------- zero init
__global__ void k_zero(float* __restrict__ p, long long n) {
  long long i = ((long long)blockIdx.x * blockDim.x + threadIdx.x) * 4;
  long long stride = (long long)gridDim.x * blockDim.x * 4;
  for (; i + 3 < n; i += stride) {
    *(float4*)(p + i) = make_float4(0.f, 0.f, 0.f, 0.f);
  }
}

// ---------------------------------------------------------------- weight fold
// p0: Wk ; p1: Wq·rel_attT scaled by rel_pri*2.5 ; p2..4: Wq·wm_mT ; p5: Wv·rel_msg
__global__ __launch_bounds__(256) void k_transform(
    const float* __restrict__ Wk, const float* __restrict__ bk,
    const float* __restrict__ Wq, const float* __restrict__ bq,
    const float* __restrict__ Wv, const float* __restrict__ bv,
    const float* __restrict__ rel_att, const float* __restrict__ rel_msg,
    const float* __restrict__ rel_pri,
    const float* __restrict__ wm0, const float* __restrict__ wm1,
    const float* __restrict__ wm2,
    unsigned short* __restrict__ Wt_all, float* __restrict__ bias_all)
{
  int gid = blockIdx.x * 256 + threadIdx.x;
  if (gid >= 6 * 128 * 128) return;
  int p = gid >> 14;
  int idx = gid & 16383;
  int c = idx >> 7, k = idx & 127;
  int h = c >> 4, r = c & 15;
  float wsum = 0.f, bsum = 0.f;
  if (p == 0) {
    wsum = Wk[k * 128 + c];
    bsum = bk[c];
  } else if (p <= 4) {
    const float* M = (p == 1) ? rel_att : ((p == 2) ? wm0 : ((p == 3) ? wm1 : wm2));
#pragma unroll
    for (int f = 0; f < 16; f++) {
      float mv = M[h * 256 + r * 16 + f];
      wsum += Wq[k * 128 + h * 16 + f] * mv;
      bsum += bq[h * 16 + f] * mv;
    }
    if (p == 1) { float sc = rel_pri[h] * 2.5f; wsum *= sc; bsum *= sc; }
  } else {
#pragma unroll
    for (int d = 0; d < 16; d++) {
      float mv = rel_msg[h * 256 + d * 16 + r];
      wsum += Wv[k * 128 + h * 16 + d] * mv;
      bsum += bv[h * 16 + d] * mv;
    }
  }
  Wt_all[(size_t)p * 16384 + c * 128 + k] = f2bf(wsum);
  if (k == 0) bias_all[p * 128 + c] = bsum;
}

// ---------------------------------------------------------------- projections
// grid (rowtiles, 3 modalities); A-frags held in registers across the 4 planes.
// P[plane][N][128] bf16, plane = pt*3+m: pt 0=K, 1=QA(pri-scaled), 2=QW_m, 3=VM.
__global__ __launch_bounds__(256) void k_proj(
    const float* __restrict__ x0, const float* __restrict__ x1,
    const float* __restrict__ x2,
    const unsigned short* __restrict__ Wt_all, const float* __restrict__ bias_all,
    unsigned short* __restrict__ P, int N)
{
  __shared__ __attribute__((aligned(16))) unsigned short Wt[128 * 136];
  int m = blockIdx.y;
  const float* X = (m == 0) ? x0 : ((m == 1) ? x1 : x2);
  int tid = threadIdx.x;
  int wave = tid >> 6, lane = tid & 63;
  int quad = lane >> 4, l16 = lane & 15;
  int row0 = blockIdx.x * 64 + wave * 16;
  int arow = row0 + l16; if (arow >= N) arow = N - 1;
  const float* ap = X + (size_t)arow * D;
  bf16x8 afr[4];
#pragma unroll
  for (int kk4 = 0; kk4 < 4; kk4++) {
    float4 f0 = *(const float4*)(ap + kk4 * 32 + quad * 8);
    float4 f1 = *(const float4*)(ap + kk4 * 32 + quad * 8 + 4);
    ushortx8 uu;
    uu[0]=f2bf(f0.x); uu[1]=f2bf(f0.y); uu[2]=f2bf(f0.z); uu[3]=f2bf(f0.w);
    uu[4]=f2bf(f1.x); uu[5]=f2bf(f1.y); uu[6]=f2bf(f1.z); uu[7]=f2bf(f1.w);
    afr[kk4] = __builtin_bit_cast(bf16x8, uu);
  }
  for (int pt = 0; pt < 4; pt++) {
    int wp = (pt == 0) ? 0 : ((pt == 1) ? 1 : ((pt == 2) ? (2 + m) : 5));
    const unsigned short* Wsrc = Wt_all + (size_t)wp * 16384;
    const float* B = bias_all + wp * 128;
    __syncthreads();
    for (int idx = tid; idx < 128 * 128; idx += 256) {
      int c = idx >> 7, k = idx & 127;
      Wt[c * 136 + k] = Wsrc[idx];
    }
    __syncthreads();
    floatx4 acc[8];
#pragma unroll
    for (int ct = 0; ct < 8; ct++) acc[ct] = (floatx4)0.f;
#pragma unroll
    for (int kk4 = 0; kk4 < 4; kk4++) {
#pragma unroll
      for (int ct = 0; ct < 8; ct++) {
        uint4 bu = *(const uint4*)(&Wt[(ct * 16 + l16) * 136 + kk4 * 32 + quad * 8]);
        bf16x8 bf = __builtin_bit_cast(bf16x8, bu);
        acc[ct] = __builtin_amdgcn_mfma_f32_16x16x32_bf16(afr[kk4], bf, acc[ct], 0, 0, 0);
      }
    }
    unsigned short* Pout = P + (size_t)(pt * 3 + m) * N * D;
#pragma unroll
    for (int ct = 0; ct < 8; ct++) {
      int col = ct * 16 + l16;
      float bias = B[col];
#pragma unroll
      for (int i = 0; i < 4; i++) {
        int r = row0 + quad * 4 + i;
        if (r < N) Pout[(size_t)r * D + col] = f2bf(acc[ct][i] + bias);
      }
    }
  }
}

// ---------------------------------------------------------------- CSR build
__global__ void k_hist(const int* __restrict__ dst, int* __restrict__ counts, int E) {
  int e = blockIdx.x * 256 + threadIdx.x;
  if (e < E) atomicAdd(&counts[dst[e]], 1);
}

__global__ __launch_bounds__(1024) void k_scan_part(
    const int* __restrict__ counts, int* __restrict__ row_start,
    int* __restrict__ partials, int N)
{
  __shared__ int wsum[16];
  int tid = threadIdx.x;
  int gi = blockIdx.x * 1024 + tid;
  int v = (gi < N) ? counts[gi] : 0;
  int lane = tid & 63, wid = tid >> 6;
  int x = v;
#pragma unroll
  for (int off = 1; off < 64; off <<= 1) {
    int y = __shfl_up(x, off, 64);
    if (lane >= off) x += y;
  }
  if (lane == 63) wsum[wid] = x;
  __syncthreads();
  if (wid == 0) {
    int ws = (lane < 16) ? wsum[lane] : 0;
#pragma unroll
    for (int off = 1; off < 16; off <<= 1) {
      int y = __shfl_up(ws, off, 64);
      if (lane >= off) ws += y;
    }
    if (lane < 16) wsum[lane] = ws;
  }
  __syncthreads();
  int excl = x - v + (wid > 0 ? wsum[wid - 1] : 0);
  if (gi <= N) row_start[gi] = excl;
  if (tid == 0) partials[blockIdx.x] = wsum[15];
}

__global__ __launch_bounds__(1024) void k_scan_fix(
    int* __restrict__ row_start, const int* __restrict__ partials, int N, int nb)
{
  __shared__ int offs[64];
  int tid = threadIdx.x;
  if (tid == 0) {
    int acc = 0;
    for (int b = 0; b < nb; b++) { offs[b] = acc; acc += partials[b]; }
  }
  __syncthreads();
  for (int i = tid; i <= N; i += 1024) row_start[i] += offs[i >> 10];
}

// scatter src ids directly into CSR order (no eidx indirection later)
__global__ void k_scatter(const int* __restrict__ dst, const int* __restrict__ src,
                          const int* __restrict__ row_start,
                          int* __restrict__ cursor, int* __restrict__ src_sorted, int E) {
  int e = blockIdx.x * 256 + threadIdx.x;
  if (e < E) {
    int d = dst[e];
    int pos = atomicAdd(&cursor[d], 1);
    src_sorted[row_start[d] + pos] = src[e];
  }
}

// ---------------------------------------------------------------- fused node kernel
__device__ __forceinline__ void edge_vals(
    const unsigned short* __restrict__ P, size_t Nsz, int s, int h,
    const uint4 (&qa)[3][2], const uint4 (&qw)[3][2],
    float (&av)[3], float (&lv)[3])
{
#pragma unroll
  for (int m = 0; m < 3; m++) {
    const unsigned short* kp = P + ((size_t)m * Nsz + s) * 128 + h * 16;
    uint4 k0 = *(const uint4*)kp, k1 = *(const uint4*)(kp + 8);
    const unsigned int* ka = (const unsigned int*)&k0;
    const unsigned int* kb = (const unsigned int*)&k1;
    const unsigned int* a0 = (const unsigned int*)&qa[m][0];
    const unsigned int* a1 = (const unsigned int*)&qa[m][1];
    const unsigned int* w0 = (const unsigned int*)&qw[m][0];
    const unsigned int* w1 = (const unsigned int*)&qw[m][1];
    float da = 0.f, dw = 0.f;
#pragma unroll
    for (int j = 0; j < 4; j++) {
      acc2(ka[j], a0[j], da); acc2(kb[j], a1[j], da);
      acc2(ka[j], w0[j], dw); acc2(kb[j], w1[j], dw);
    }
    av[m] = da;          // rel_pri*2.5 folded into QA plane
    lv[m] = dw;
  }
  float mx = fmaxf(lv[0], fmaxf(lv[1], lv[2]));
  float e0 = __expf(lv[0] - mx), e1 = __expf(lv[1] - mx), e2 = __expf(lv[2] - mx);
  float inv = 1.f / (e0 + e1 + e2);
  lv[0] = e0 * inv; lv[1] = e1 * inv; lv[2] = e2 * inv;
}

__global__ __launch_bounds__(256) void k_node(
    const unsigned short* __restrict__ P,
    const int* __restrict__ row_start, const int* __restrict__ srcs,
    unsigned short* __restrict__ hagg, int N, int E)
{
  int tid = threadIdx.x;
  int wave = tid >> 6, lane = tid & 63;
  int n = blockIdx.x * 4 + wave;
  if (n >= N) return;
  int ro = row_start[n];
  int deg = row_start[n + 1] - ro;
  float acc00 = 0, acc01 = 0, acc10 = 0, acc11 = 0, acc20 = 0, acc21 = 0;
  if (deg > 0) {
    int h = lane & 7, slot = lane >> 3;
    size_t Nsz = (size_t)N;
    uint4 qa[3][2], qw[3][2];
#pragma unroll
    for (int m = 0; m < 3; m++) {
      const unsigned short* qap = P + ((size_t)(3 + m) * Nsz + n) * 128 + h * 16;
      const unsigned short* qwp = P + ((size_t)(6 + m) * Nsz + n) * 128 + h * 16;
      qa[m][0] = *(const uint4*)qap; qa[m][1] = *(const uint4*)(qap + 8);
      qw[m][0] = *(const uint4*)qwp; qw[m][1] = *(const uint4*)(qwp + 8);
    }
    int nch = (deg + 7) >> 3;
    float cX0[8] = {}, cX1[8] = {}, cX2[8] = {}, cEa[8] = {}, cT[8] = {};
    int cS[8] = {};
    // ---- phase 1: sumA_m, sumAl
    float sA0 = 0, sA1 = 0, sA2 = 0, sAl = 0;
#pragma unroll
    for (int c = 0; c < 8; c++) {
      int idx = c * 8 + slot;
      if (c < nch && idx < deg) {
        int s = srcs[ro + idx]; cS[c] = s;
        float av[3], lv[3];
        edge_vals(P, Nsz, s, h, qa, qw, av, lv);
        float e0 = __expf(av[0]), e1 = __expf(av[1]), e2 = __expf(av[2]);
        float align = -(fabsf(av[0]-av[1]) + fabsf(av[0]-av[2]) + fabsf(av[1]-av[2])) * (1.f/3.f);
        float ea = __expf(align);
        cX0[c] = lv[0] * e0; cX1[c] = lv[1] * e1; cX2[c] = lv[2] * e2; cEa[c] = ea;
        sA0 += e0; sA1 += e1; sA2 += e2; sAl += ea;
      }
    }
    for (int c = 8; c < nch; c++) {          // rare deg>64 fallback
      int idx = c * 8 + slot;
      if (idx < deg) {
        int s = srcs[ro + idx];
        float av[3], lv[3];
        edge_vals(P, Nsz, s, h, qa, qw, av, lv);
        float align = -(fabsf(av[0]-av[1]) + fabsf(av[0]-av[2]) + fabsf(av[1]-av[2])) * (1.f/3.f);
        sA0 += __expf(av[0]); sA1 += __expf(av[1]); sA2 += __expf(av[2]);
        sAl += __expf(align);
      }
    }
#pragma unroll
    for (int off = 8; off < 64; off <<= 1) {
      sA0 += __shfl_xor(sA0, off, 64);
      sA1 += __shfl_xor(sA1, off, 64);
      sA2 += __shfl_xor(sA2, off, 64);
      sAl += __shfl_xor(sAl, off, 64);
    }
    float rA0 = 1.f / fmaxf(sA0, 1e-30f), rA1 = 1.f / fmaxf(sA1, 1e-30f);
    float rA2 = 1.f / fmaxf(sA2, 1e-30f), rAl = 1.f / fmaxf(sAl, 1e-30f);
    // ---- phase 2: sumT
    float sT = 0;
#pragma unroll
    for (int c = 0; c < 8; c++) {
      int idx = c * 8 + slot;
      if (c < nch && idx < deg) {
        float t = (cX0[c] * rA0 + cX1[c] * rA1 + cX2[c] * rA2) * (cEa[c] * rAl);
        cT[c] = t;
        sT += __expf(t);
      }
    }
    for (int c = 8; c < nch; c++) {
      int idx = c * 8 + slot;
      if (idx < deg) {
        int s = srcs[ro + idx];
        float av[3], lv[3];
        edge_vals(P, Nsz, s, h, qa, qw, av, lv);
        float align = -(fabsf(av[0]-av[1]) + fabsf(av[0]-av[2]) + fabsf(av[1]-av[2])) * (1.f/3.f);
        float t = (lv[0]*__expf(av[0])*rA0 + lv[1]*__expf(av[1])*rA1 + lv[2]*__expf(av[2])*rA2)
                  * (__expf(align) * rAl);
        sT += __expf(t);
      }
    }
#pragma unroll
    for (int off = 8; off < 64; off <<= 1) sT += __shfl_xor(sT, off, 64);
    float rT = 1.f / fmaxf(sT, 1e-30f);
    // ---- phase 3: beta + aggregation, fully unrolled + predicated
    const unsigned int* Pu = (const unsigned int*)P;
    int hl = lane >> 3;
#pragma unroll
    for (int c = 0; c < 8; c++) {
      if (c < nch) {
        int idx = c * 8 + slot;
        float beta = (idx < deg) ? __expf(cT[c]) * rT : 0.f;
        int sv = cS[c];          // 0 for invalid slots (cached node-0 row, b=0)
        float bj[8]; int sj[8];
#pragma unroll
        for (int jj = 0; jj < 8; jj++) {
          bj[jj] = __shfl(beta, jj * 8 + hl, 64);
          sj[jj] = __shfl(sv, jj * 8, 64);
        }
#pragma unroll
        for (int jj = 0; jj < 8; jj++) {
          size_t base9 = ((size_t)9 * Nsz + sj[jj]) * 64 + lane;
          unsigned int u0 = Pu[base9];
          unsigned int u1 = Pu[base9 + Nsz * 64];
          unsigned int u2 = Pu[base9 + 2 * Nsz * 64];
          float b = bj[jj];
          acc00 += b * bf2f((unsigned short)u0); acc01 += b * bf2f((unsigned short)(u0 >> 16));
          acc10 += b * bf2f((unsigned short)u1); acc11 += b * bf2f((unsigned short)(u1 >> 16));
          acc20 += b * bf2f((unsigned short)u2); acc21 += b * bf2f((unsigned short)(u2 >> 16));
        }
      }
    }
    for (int c = 8; c < nch; c++) {          // rare deg>64 fallback
      int idx = c * 8 + slot;
      float beta = 0.f; int sv = 0;
      if (idx < deg) {
        sv = srcs[ro + idx];
        float av[3], lv[3];
        edge_vals(P, Nsz, sv, h, qa, qw, av, lv);
        float align = -(fabsf(av[0]-av[1]) + fabsf(av[0]-av[2]) + fabsf(av[1]-av[2])) * (1.f/3.f);
        float t = (lv[0]*__expf(av[0])*rA0 + lv[1]*__expf(av[1])*rA1 + lv[2]*__expf(av[2])*rA2)
                  * (__expf(align) * rAl);
        beta = __expf(t) * rT;
      }
      int jmax = min(8, deg - c * 8);
      for (int jj = 0; jj < jmax; jj++) {
        float b = __shfl(beta, jj * 8 + hl, 64);
        int s = __shfl(sv, jj * 8, 64);
        size_t base9 = ((size_t)9 * Nsz + s) * 64 + lane;
        unsigned int u0 = Pu[base9];
        unsigned int u1 = Pu[base9 + Nsz * 64];
        unsigned int u2 = Pu[base9 + 2 * Nsz * 64];
        acc00 += b * bf2f((unsigned short)u0); acc01 += b * bf2f((unsigned short)(u0 >> 16));
        acc10 += b * bf2f((unsigned short)u1); acc11 += b * bf2f((unsigned short)(u1 >> 16));
        acc20 += b * bf2f((unsigned short)u2); acc21 += b * bf2f((unsigned short)(u2 >> 16));
      }
    }
  }
  unsigned int* ho = (unsigned int*)hagg;
  ho[((size_t)0 * N + n) * 64 + lane] = ((unsigned int)f2bf(acc01) << 16) | f2bf(acc00);
  ho[((size_t)1 * N + n) * 64 + lane] = ((unsigned int)f2bf(acc11) << 16) | f2bf(acc10);
  ho[((size_t)2 * N + n) * 64 + lane] = ((unsigned int)f2bf(acc21) << 16) | f2bf(acc20);
}

// ---------------------------------------------------------------- output GEMM
__global__ __launch_bounds__(256) void k_out(
    const unsigned short* __restrict__ Hagg, const float* __restrict__ Wa,
    const float* __restrict__ ba,
    const float* __restrict__ x0, const float* __restrict__ x1,
    const float* __restrict__ x2, const float* __restrict__ skip,
    float* __restrict__ out, int N)
{
  __shared__ __attribute__((aligned(16))) unsigned short Wt[128 * 136];
  int m = blockIdx.y;
  const float* X = (m == 0) ? x0 : ((m == 1) ? x1 : x2);
  int tid = threadIdx.x;
  for (int idx = tid; idx < 128 * 128; idx += 256) {
    int k = idx >> 7, c = idx & 127;
    Wt[c * 136 + k] = f2bf(Wa[idx]);
  }
  __syncthreads();
  float alpha = 1.f / (1.f + __expf(-skip[0]));
  float oma = 1.f - alpha;
  int wave = tid >> 6, lane = tid & 63;
  int quad = lane >> 4, l16 = lane & 15;
  int row0 = blockIdx.x * 64 + wave * 16;
  int arow = row0 + l16; if (arow >= N) arow = N - 1;
  const unsigned short* hp = Hagg + ((size_t)m * N + arow) * D;
  floatx4 acc[8];
#pragma unroll
  for (int ct = 0; ct < 8; ct++) acc[ct] = (floatx4)0.f;
#pragma unroll
  for (int kk = 0; kk < 128; kk += 32) {
    uint4 au = *(const uint4*)(hp + kk + quad * 8);
    bf16x8 af = __builtin_bit_cast(bf16x8, au);
#pragma unroll
    for (int ct = 0; ct < 8; ct++) {
      uint4 bu = *(const uint4*)(&Wt[(ct * 16 + l16) * 136 + kk + quad * 8]);
      bf16x8 bf = __builtin_bit_cast(bf16x8, bu);
      acc[ct] = __builtin_amdgcn_mfma_f32_16x16x32_bf16(af, bf, acc[ct], 0, 0, 0);
    }
  }
  float* om = out + (size_t)m * N * D;
#pragma unroll
  for (int ct = 0; ct < 8; ct++) {
    int col = ct * 16 + l16;
    float bias = ba[col];
#pragma unroll
    for (int i = 0; i < 4; i++) {
      int r = row0 + quad * 4 + i;
      if (r < N) {
        om[(size_t)r * D + col] =
            (acc[ct][i] + bias) * alpha + X[(size_t)r * D + col] * oma;
      }
    }
  }
}

// ---------------------------------------------------------------- launch
extern "C" void kernel_launch(void* const* d_in, const int* in_sizes, int n_in,
                              void* d_out, int out_size, void* d_ws, size_t ws_size,
                              hipStream_t stream) {
  const float* x0 = (const float*)d_in[0];
  const float* x1 = (const float*)d_in[1];
  const float* x2 = (const float*)d_in[2];
  const float* Wk = (const float*)d_in[3];
  const float* bk = (const float*)d_in[4];
  const float* Wq = (const float*)d_in[5];
  const float* bq = (const float*)d_in[6];
  const float* Wv = (const float*)d_in[7];
  const float* bv = (const float*)d_in[8];
  const float* Wa = (const float*)d_in[9];
  const float* ba = (const float*)d_in[10];
  const float* rel_att = (const float*)d_in[11];
  const float* rel_msg = (const float*)d_in[12];
  const float* rel_pri = (const float*)d_in[13];
  const float* wm0 = (const float*)d_in[14];
  const float* wm1 = (const float*)d_in[15];
  const float* wm2 = (const float*)d_in[16];
  const float* skip = (const float*)d_in[17];
  const int* src = (const int*)d_in[18];
  const int* dstv = (const int*)d_in[19];
  int N = in_sizes[0] / D;      // 20000
  int E = in_sizes[18];         // 160000

  char* wsb = (char*)d_ws;
  size_t off = 0;
  auto alloc = [&](size_t bytes) { size_t o = off; off += (bytes + 63) & ~(size_t)63; return o; };
  unsigned short* P         = (unsigned short*)(wsb + alloc((size_t)12 * N * D * 2));
  unsigned short* Wt_all    = (unsigned short*)(wsb + alloc((size_t)6 * 16384 * 2));
  float*          bias_all  = (float*)(wsb + alloc((size_t)6 * 128 * 4));
  int*            cnt2      = (int*)(wsb + alloc((size_t)2 * N * 4));   // counts | cursor
  int*            row_start = (int*)(wsb + alloc((size_t)(N + 1) * 4));
  int*            src_sorted= (int*)(wsb + alloc((size_t)E * 4));
  int*            partials  = (int*)(wsb + alloc((size_t)64 * 4));
  unsigned short* hagg      = (unsigned short*)(wsb + alloc((size_t)3 * N * D * 2));
  int* counts = cnt2;
  int* cursor = cnt2 + N;

  k_zero<<<dim3(40), 256, 0, stream>>>((float*)cnt2, (long long)2 * N);
  k_transform<<<dim3(384), 256, 0, stream>>>(
      Wk, bk, Wq, bq, Wv, bv, rel_att, rel_msg, rel_pri, wm0, wm1, wm2, Wt_all, bias_all);
  k_proj<<<dim3((N + 63) / 64, 3), 256, 0, stream>>>(
      x0, x1, x2, Wt_all, bias_all, P, N);
  k_hist<<<dim3((E + 255) / 256), 256, 0, stream>>>(dstv, counts, E);
  int nb = (N + 1024) / 1024;
  k_scan_part<<<dim3(nb), 1024, 0, stream>>>(counts, row_start, partials, N);
  k_scan_fix<<<dim3(1), 1024, 0, stream>>>(row_start, partials, N, nb);
  k_scatter<<<dim3((E + 255) / 256), 256, 0, stream>>>(dstv, src, row_start, cursor, src_sorted, E);
  k_node<<<dim3((N + 3) / 4), 256, 0, stream>>>(
      P, row_start, src_sorted, hagg, N, E);
  k_out<<<dim3((N + 63) / 64, 3), 256, 0, stream>>>(
      hagg, Wa, ba, x0, x1, x2, skip, (float*)d_out, N);
}

// Round 6
// 256.282 us; speedup vs baseline: 14.3536x; 1.0962x over previous
//
#include <hip/hip_runtime.h>

#define D 128
#define NH 8

typedef __bf16 bf16x8 __attribute__((ext_vector_type(8)));
typedef unsigned short ushortx8 __attribute__((ext_vector_type(8)));
typedef float floatx4 __attribute__((ext_vector_type(4)));

__device__ __forceinline__ float bf2f(unsigned short u) {
  union { unsigned int i; float f; } x; x.i = ((unsigned int)u) << 16; return x.f;
}
__device__ __forceinline__ unsigned short f2bf(float f) {
  union { float f; unsigned int i; } x; x.f = f;
  unsigned int i = x.i;
  return (unsigned short)((i + 0x7FFFu + ((i >> 16) & 1u)) >> 16);
}
// accumulate both bf16 halves of packed uints into s
__device__ __forceinline__ void acc2(unsigned int ku, unsigned int qu, float& s) {
  union { unsigned int i; float f; } a, b;
  a.i = ku << 16;          b.i = qu << 16;          s += a.f * b.f;
  a.i = ku & 0xffff0000u;  b.i = qu & 0xffff0000u;  s += a.f * b.f;
}

// ---------------------------------------------------------------- transform + hist (merged)
// blocks [0,384): weight fold -> Wt_all planes
//   p0: Wk ; p1: Wq·rel_attT scaled rel_pri*2.5 ; p2..4: Wq·wm_mT ; p5: Wv·rel_msg
// blocks [384,...): histogram of dst into counts (counts pre-zeroed by memset)
__global__ __launch_bounds__(256) void k_misc(
    const float* __restrict__ Wk, const float* __restrict__ bk,
    const float* __restrict__ Wq, const float* __restrict__ bq,
    const float* __restrict__ Wv, const float* __restrict__ bv,
    const float* __restrict__ rel_att, const float* __restrict__ rel_msg,
    const float* __restrict__ rel_pri,
    const float* __restrict__ wm0, const float* __restrict__ wm1,
    const float* __restrict__ wm2,
    unsigned short* __restrict__ Wt_all, float* __restrict__ bias_all,
    const int* __restrict__ dst, int* __restrict__ counts, int E)
{
  int b = blockIdx.x;
  if (b >= 384) {
    int e = (b - 384) * 256 + threadIdx.x;
    if (e < E) atomicAdd(&counts[dst[e]], 1);
    return;
  }
  int gid = b * 256 + threadIdx.x;
  if (gid >= 6 * 128 * 128) return;
  int p = gid >> 14;
  int idx = gid & 16383;
  int c = idx >> 7, k = idx & 127;
  int h = c >> 4, r = c & 15;
  float wsum = 0.f, bsum = 0.f;
  if (p == 0) {
    wsum = Wk[k * 128 + c];
    bsum = bk[c];
  } else if (p <= 4) {
    const float* M = (p == 1) ? rel_att : ((p == 2) ? wm0 : ((p == 3) ? wm1 : wm2));
#pragma unroll
    for (int f = 0; f < 16; f++) {
      float mv = M[h * 256 + r * 16 + f];
      wsum += Wq[k * 128 + h * 16 + f] * mv;
      bsum += bq[h * 16 + f] * mv;
    }
    if (p == 1) { float sc = rel_pri[h] * 2.5f; wsum *= sc; bsum *= sc; }
  } else {
#pragma unroll
    for (int d = 0; d < 16; d++) {
      float mv = rel_msg[h * 256 + d * 16 + r];
      wsum += Wv[k * 128 + h * 16 + d] * mv;
      bsum += bv[h * 16 + d] * mv;
    }
  }
  Wt_all[(size_t)p * 16384 + c * 128 + k] = f2bf(wsum);
  if (k == 0) bias_all[p * 128 + c] = bsum;
}

// ---------------------------------------------------------------- projections
// grid (rowtiles, 3 modalities); A-frags in registers across the 4 planes;
// vectorized uint4 LDS staging (8 iters/plane).
__global__ __launch_bounds__(256) void k_proj(
    const float* __restrict__ x0, const float* __restrict__ x1,
    const float* __restrict__ x2,
    const unsigned short* __restrict__ Wt_all, const float* __restrict__ bias_all,
    unsigned short* __restrict__ P, int N)
{
  __shared__ __attribute__((aligned(16))) unsigned short Wt[128 * 136];
  int m = blockIdx.y;
  const float* X = (m == 0) ? x0 : ((m == 1) ? x1 : x2);
  int tid = threadIdx.x;
  int wave = tid >> 6, lane = tid & 63;
  int quad = lane >> 4, l16 = lane & 15;
  int row0 = blockIdx.x * 64 + wave * 16;
  int arow = row0 + l16; if (arow >= N) arow = N - 1;
  const float* ap = X + (size_t)arow * D;
  bf16x8 afr[4];
#pragma unroll
  for (int kk4 = 0; kk4 < 4; kk4++) {
    float4 f0 = *(const float4*)(ap + kk4 * 32 + quad * 8);
    float4 f1 = *(const float4*)(ap + kk4 * 32 + quad * 8 + 4);
    ushortx8 uu;
    uu[0]=f2bf(f0.x); uu[1]=f2bf(f0.y); uu[2]=f2bf(f0.z); uu[3]=f2bf(f0.w);
    uu[4]=f2bf(f1.x); uu[5]=f2bf(f1.y); uu[6]=f2bf(f1.z); uu[7]=f2bf(f1.w);
    afr[kk4] = __builtin_bit_cast(bf16x8, uu);
  }
  for (int pt = 0; pt < 4; pt++) {
    int wp = (pt == 0) ? 0 : ((pt == 1) ? 1 : ((pt == 2) ? (2 + m) : 5));
    const unsigned short* Wsrc = Wt_all + (size_t)wp * 16384;
    const float* B = bias_all + wp * 128;
    __syncthreads();
#pragma unroll
    for (int it = 0; it < 8; it++) {              // 2048 uint4 = 32 KB
      int idx = it * 256 + tid;
      int c = idx >> 4, kc = (idx & 15) << 3;
      *(uint4*)(&Wt[c * 136 + kc]) = *(const uint4*)(&Wsrc[c * 128 + kc]);
    }
    __syncthreads();
    floatx4 acc[8];
#pragma unroll
    for (int ct = 0; ct < 8; ct++) acc[ct] = (floatx4)0.f;
#pragma unroll
    for (int kk4 = 0; kk4 < 4; kk4++) {
#pragma unroll
      for (int ct = 0; ct < 8; ct++) {
        uint4 bu = *(const uint4*)(&Wt[(ct * 16 + l16) * 136 + kk4 * 32 + quad * 8]);
        bf16x8 bf = __builtin_bit_cast(bf16x8, bu);
        acc[ct] = __builtin_amdgcn_mfma_f32_16x16x32_bf16(afr[kk4], bf, acc[ct], 0, 0, 0);
      }
    }
    unsigned short* Pout = P + (size_t)(pt * 3 + m) * N * D;
#pragma unroll
    for (int ct = 0; ct < 8; ct++) {
      int col = ct * 16 + l16;
      float bias = B[col];
#pragma unroll
      for (int i = 0; i < 4; i++) {
        int r = row0 + quad * 4 + i;
        if (r < N) Pout[(size_t)r * D + col] = f2bf(acc[ct][i] + bias);
      }
    }
  }
}

// ---------------------------------------------------------------- CSR build
__global__ __launch_bounds__(1024) void k_scan_part(
    const int* __restrict__ counts, int* __restrict__ row_start,
    int* __restrict__ partials, int N)
{
  __shared__ int wsum[16];
  int tid = threadIdx.x;
  int gi = blockIdx.x * 1024 + tid;
  int v = (gi < N) ? counts[gi] : 0;
  int lane = tid & 63, wid = tid >> 6;
  int x = v;
#pragma unroll
  for (int off = 1; off < 64; off <<= 1) {
    int y = __shfl_up(x, off, 64);
    if (lane >= off) x += y;
  }
  if (lane == 63) wsum[wid] = x;
  __syncthreads();
  if (wid == 0) {
    int ws = (lane < 16) ? wsum[lane] : 0;
#pragma unroll
    for (int off = 1; off < 16; off <<= 1) {
      int y = __shfl_up(ws, off, 64);
      if (lane >= off) ws += y;
    }
    if (lane < 16) wsum[lane] = ws;
  }
  __syncthreads();
  int excl = x - v + (wid > 0 ? wsum[wid - 1] : 0);
  if (gi <= N) row_start[gi] = excl;
  if (tid == 0) partials[blockIdx.x] = wsum[15];
}

__global__ __launch_bounds__(1024) void k_scan_fix(
    int* __restrict__ row_start, const int* __restrict__ partials, int N, int nb)
{
  __shared__ int offs[64];
  int tid = threadIdx.x;
  if (tid == 0) {
    int acc = 0;
    for (int b = 0; b < nb; b++) { offs[b] = acc; acc += partials[b]; }
  }
  __syncthreads();
  for (int i = tid; i <= N; i += 1024) row_start[i] += offs[i >> 10];
}

// scatter src ids directly into CSR order
__global__ void k_scatter(const int* __restrict__ dst, const int* __restrict__ src,
                          const int* __restrict__ row_start,
                          int* __restrict__ cursor, int* __restrict__ src_sorted, int E) {
  int e = blockIdx.x * 256 + threadIdx.x;
  if (e < E) {
    int d = dst[e];
    int pos = atomicAdd(&cursor[d], 1);
    src_sorted[row_start[d] + pos] = src[e];
  }
}

// ---------------------------------------------------------------- fused node kernel
__device__ __forceinline__ void edge_vals(
    const unsigned short* __restrict__ P, size_t Nsz, int s, int h,
    const uint4 (&qa)[3][2], const uint4 (&qw)[3][2],
    float (&av)[3], float (&lv)[3])
{
#pragma unroll
  for (int m = 0; m < 3; m++) {
    const unsigned short* kp = P + ((size_t)m * Nsz + s) * 128 + h * 16;
    uint4 k0 = *(const uint4*)kp, k1 = *(const uint4*)(kp + 8);
    const unsigned int* ka = (const unsigned int*)&k0;
    const unsigned int* kb = (const unsigned int*)&k1;
    const unsigned int* a0 = (const unsigned int*)&qa[m][0];
    const unsigned int* a1 = (const unsigned int*)&qa[m][1];
    const unsigned int* w0 = (const unsigned int*)&qw[m][0];
    const unsigned int* w1 = (const unsigned int*)&qw[m][1];
    float da = 0.f, dw = 0.f;
#pragma unroll
    for (int j = 0; j < 4; j++) {
      acc2(ka[j], a0[j], da); acc2(kb[j], a1[j], da);
      acc2(ka[j], w0[j], dw); acc2(kb[j], w1[j], dw);
    }
    av[m] = da;          // rel_pri*2.5 folded into QA plane
    lv[m] = dw;
  }
  float mx = fmaxf(lv[0], fmaxf(lv[1], lv[2]));
  float e0 = __expf(lv[0] - mx), e1 = __expf(lv[1] - mx), e2 = __expf(lv[2] - mx);
  float inv = 1.f / (e0 + e1 + e2);
  lv[0] = e0 * inv; lv[1] = e1 * inv; lv[2] = e2 * inv;
}

// one wave per dst node; 4-chunk register cache (deg<=32 fast path) to keep
// VGPR ~92 (5 waves/SIMD); fallback recompute loop for deg>32.
__global__ __launch_bounds__(256) void k_node(
    const unsigned short* __restrict__ P,
    const int* __restrict__ row_start, const int* __restrict__ srcs,
    unsigned short* __restrict__ hagg, int N, int E)
{
  int tid = threadIdx.x;
  int wave = tid >> 6, lane = tid & 63;
  int n = blockIdx.x * 4 + wave;
  if (n >= N) return;
  int ro = row_start[n];
  int deg = row_start[n + 1] - ro;
  float acc00 = 0, acc01 = 0, acc10 = 0, acc11 = 0, acc20 = 0, acc21 = 0;
  if (deg > 0) {
    int h = lane & 7, slot = lane >> 3;
    size_t Nsz = (size_t)N;
    uint4 qa[3][2], qw[3][2];
#pragma unroll
    for (int m = 0; m < 3; m++) {
      const unsigned short* qap = P + ((size_t)(3 + m) * Nsz + n) * 128 + h * 16;
      const unsigned short* qwp = P + ((size_t)(6 + m) * Nsz + n) * 128 + h * 16;
      qa[m][0] = *(const uint4*)qap; qa[m][1] = *(const uint4*)(qap + 8);
      qw[m][0] = *(const uint4*)qwp; qw[m][1] = *(const uint4*)(qwp + 8);
    }
    int nch = (deg + 7) >> 3;
    float cX0[4] = {}, cX1[4] = {}, cX2[4] = {}, cEa[4] = {}, cT[4] = {};
    int cS[4] = {};
    // ---- phase 1: sumA_m, sumAl
    float sA0 = 0, sA1 = 0, sA2 = 0, sAl = 0;
#pragma unroll
    for (int c = 0; c < 4; c++) {
      int idx = c * 8 + slot;
      if (c < nch && idx < deg) {
        int s = srcs[ro + idx]; cS[c] = s;
        float av[3], lv[3];
        edge_vals(P, Nsz, s, h, qa, qw, av, lv);
        float e0 = __expf(av[0]), e1 = __expf(av[1]), e2 = __expf(av[2]);
        float align = -(fabsf(av[0]-av[1]) + fabsf(av[0]-av[2]) + fabsf(av[1]-av[2])) * (1.f/3.f);
        float ea = __expf(align);
        cX0[c] = lv[0] * e0; cX1[c] = lv[1] * e1; cX2[c] = lv[2] * e2; cEa[c] = ea;
        sA0 += e0; sA1 += e1; sA2 += e2; sAl += ea;
      }
    }
    for (int c = 4; c < nch; c++) {          // rare deg>32 fallback
      int idx = c * 8 + slot;
      if (idx < deg) {
        int s = srcs[ro + idx];
        float av[3], lv[3];
        edge_vals(P, Nsz, s, h, qa, qw, av, lv);
        float align = -(fabsf(av[0]-av[1]) + fabsf(av[0]-av[2]) + fabsf(av[1]-av[2])) * (1.f/3.f);
        sA0 += __expf(av[0]); sA1 += __expf(av[1]); sA2 += __expf(av[2]);
        sAl += __expf(align);
      }
    }
#pragma unroll
    for (int off = 8; off < 64; off <<= 1) {
      sA0 += __shfl_xor(sA0, off, 64);
      sA1 += __shfl_xor(sA1, off, 64);
      sA2 += __shfl_xor(sA2, off, 64);
      sAl += __shfl_xor(sAl, off, 64);
    }
    float rA0 = 1.f / fmaxf(sA0, 1e-30f), rA1 = 1.f / fmaxf(sA1, 1e-30f);
    float rA2 = 1.f / fmaxf(sA2, 1e-30f), rAl = 1.f / fmaxf(sAl, 1e-30f);
    // ---- phase 2: sumT
    float sT = 0;
#pragma unroll
    for (int c = 0; c < 4; c++) {
      int idx = c * 8 + slot;
      if (c < nch && idx < deg) {
        float t = (cX0[c] * rA0 + cX1[c] * rA1 + cX2[c] * rA2) * (cEa[c] * rAl);
        cT[c] = t;
        sT += __expf(t);
      }
    }
    for (int c = 4; c < nch; c++) {
      int idx = c * 8 + slot;
      if (idx < deg) {
        int s = srcs[ro + idx];
        float av[3], lv[3];
        edge_vals(P, Nsz, s, h, qa, qw, av, lv);
        float align = -(fabsf(av[0]-av[1]) + fabsf(av[0]-av[2]) + fabsf(av[1]-av[2])) * (1.f/3.f);
        float t = (lv[0]*__expf(av[0])*rA0 + lv[1]*__expf(av[1])*rA1 + lv[2]*__expf(av[2])*rA2)
                  * (__expf(align) * rAl);
        sT += __expf(t);
      }
    }
#pragma unroll
    for (int off = 8; off < 64; off <<= 1) sT += __shfl_xor(sT, off, 64);
    float rT = 1.f / fmaxf(sT, 1e-30f);
    // ---- phase 3: beta + aggregation, fully unrolled + predicated
    const unsigned int* Pu = (const unsigned int*)P;
    int hl = lane >> 3;
#pragma unroll
    for (int c = 0; c < 4; c++) {
      if (c < nch) {
        int idx = c * 8 + slot;
        float beta = (idx < deg) ? __expf(cT[c]) * rT : 0.f;
        int sv = cS[c];          // 0 for invalid slots (cached node-0 row, b=0)
        float bj[8]; int sj[8];
#pragma unroll
        for (int jj = 0; jj < 8; jj++) {
          bj[jj] = __shfl(beta, jj * 8 + hl, 64);
          sj[jj] = __shfl(sv, jj * 8, 64);
        }
#pragma unroll
        for (int jj = 0; jj < 8; jj++) {
          size_t base9 = ((size_t)9 * Nsz + sj[jj]) * 64 + lane;
          unsigned int u0 = Pu[base9];
          unsigned int u1 = Pu[base9 + Nsz * 64];
          unsigned int u2 = Pu[base9 + 2 * Nsz * 64];
          float b = bj[jj];
          acc00 += b * bf2f((unsigned short)u0); acc01 += b * bf2f((unsigned short)(u0 >> 16));
          acc10 += b * bf2f((unsigned short)u1); acc11 += b * bf2f((unsigned short)(u1 >> 16));
          acc20 += b * bf2f((unsigned short)u2); acc21 += b * bf2f((unsigned short)(u2 >> 16));
        }
      }
    }
    for (int c = 4; c < nch; c++) {          // rare deg>32 fallback
      int idx = c * 8 + slot;
      float beta = 0.f; int sv = 0;
      if (idx < deg) {
        sv = srcs[ro + idx];
        float av[3], lv[3];
        edge_vals(P, Nsz, sv, h, qa, qw, av, lv);
        float align = -(fabsf(av[0]-av[1]) + fabsf(av[0]-av[2]) + fabsf(av[1]-av[2])) * (1.f/3.f);
        float t = (lv[0]*__expf(av[0])*rA0 + lv[1]*__expf(av[1])*rA1 + lv[2]*__expf(av[2])*rA2)
                  * (__expf(align) * rAl);
        beta = __expf(t) * rT;
      }
      int jmax = min(8, deg - c * 8);
      for (int jj = 0; jj < jmax; jj++) {
        float b = __shfl(beta, jj * 8 + hl, 64);
        int s = __shfl(sv, jj * 8, 64);
        size_t base9 = ((size_t)9 * Nsz + s) * 64 + lane;
        unsigned int u0 = Pu[base9];
        unsigned int u1 = Pu[base9 + Nsz * 64];
        unsigned int u2 = Pu[base9 + 2 * Nsz * 64];
        acc00 += b * bf2f((unsigned short)u0); acc01 += b * bf2f((unsigned short)(u0 >> 16));
        acc10 += b * bf2f((unsigned short)u1); acc11 += b * bf2f((unsigned short)(u1 >> 16));
        acc20 += b * bf2f((unsigned short)u2); acc21 += b * bf2f((unsigned short)(u2 >> 16));
      }
    }
  }
  unsigned int* ho = (unsigned int*)hagg;
  ho[((size_t)0 * N + n) * 64 + lane] = ((unsigned int)f2bf(acc01) << 16) | f2bf(acc00);
  ho[((size_t)1 * N + n) * 64 + lane] = ((unsigned int)f2bf(acc11) << 16) | f2bf(acc10);
  ho[((size_t)2 * N + n) * 64 + lane] = ((unsigned int)f2bf(acc21) << 16) | f2bf(acc20);
}

// ---------------------------------------------------------------- output GEMM
__global__ __launch_bounds__(256) void k_out(
    const unsigned short* __restrict__ Hagg, const float* __restrict__ Wa,
    const float* __restrict__ ba,
    const float* __restrict__ x0, const float* __restrict__ x1,
    const float* __restrict__ x2, const float* __restrict__ skip,
    float* __restrict__ out, int N)
{
  __shared__ __attribute__((aligned(16))) unsigned short Wt[128 * 136];
  int m = blockIdx.y;
  const float* X = (m == 0) ? x0 : ((m == 1) ? x1 : x2);
  int tid = threadIdx.x;
#pragma unroll
  for (int it = 0; it < 16; it++) {        // float4 reads along c, 4 LDS stores
    int idx = it * 256 + tid;
    int k = idx >> 5, c4 = (idx & 31) << 2;
    float4 w = *(const float4*)(&Wa[k * 128 + c4]);
    Wt[(c4 + 0) * 136 + k] = f2bf(w.x);
    Wt[(c4 + 1) * 136 + k] = f2bf(w.y);
    Wt[(c4 + 2) * 136 + k] = f2bf(w.z);
    Wt[(c4 + 3) * 136 + k] = f2bf(w.w);
  }
  __syncthreads();
  float alpha = 1.f / (1.f + __expf(-skip[0]));
  float oma = 1.f - alpha;
  int wave = tid >> 6, lane = tid & 63;
  int quad = lane >> 4, l16 = lane & 15;
  int row0 = blockIdx.x * 64 + wave * 16;
  int arow = row0 + l16; if (arow >= N) arow = N - 1;
  const unsigned short* hp = Hagg + ((size_t)m * N + arow) * D;
  floatx4 acc[8];
#pragma unroll
  for (int ct = 0; ct < 8; ct++) acc[ct] = (floatx4)0.f;
#pragma unroll
  for (int kk = 0; kk < 128; kk += 32) {
    uint4 au = *(const uint4*)(hp + kk + quad * 8);
    bf16x8 af = __builtin_bit_cast(bf16x8, au);
#pragma unroll
    for (int ct = 0; ct < 8; ct++) {
      uint4 bu = *(const uint4*)(&Wt[(ct * 16 + l16) * 136 + kk + quad * 8]);
      bf16x8 bf = __builtin_bit_cast(bf16x8, bu);
      acc[ct] = __builtin_amdgcn_mfma_f32_16x16x32_bf16(af, bf, acc[ct], 0, 0, 0);
    }
  }
  float* om = out + (size_t)m * N * D;
#pragma unroll
  for (int ct = 0; ct < 8; ct++) {
    int col = ct * 16 + l16;
    float bias = ba[col];
#pragma unroll
    for (int i = 0; i < 4; i++) {
      int r = row0 + quad * 4 + i;
      if (r < N) {
        om[(size_t)r * D + col] =
            (acc[ct][i] + bias) * alpha + X[(size_t)r * D + col] * oma;
      }
    }
  }
}

// ---------------------------------------------------------------- launch
extern "C" void kernel_launch(void* const* d_in, const int* in_sizes, int n_in,
                              void* d_out, int out_size, void* d_ws, size_t ws_size,
                              hipStream_t stream) {
  const float* x0 = (const float*)d_in[0];
  const float* x1 = (const float*)d_in[1];
  const float* x2 = (const float*)d_in[2];
  const float* Wk = (const float*)d_in[3];
  const float* bk = (const float*)d_in[4];
  const float* Wq = (const float*)d_in[5];
  const float* bq = (const float*)d_in[6];
  const float* Wv = (const float*)d_in[7];
  const float* bv = (const float*)d_in[8];
  const float* Wa = (const float*)d_in[9];
  const float* ba = (const float*)d_in[10];
  const float* rel_att = (const float*)d_in[11];
  const float* rel_msg = (const float*)d_in[12];
  const float* rel_pri = (const float*)d_in[13];
  const float* wm0 = (const float*)d_in[14];
  const float* wm1 = (const float*)d_in[15];
  const float* wm2 = (const float*)d_in[16];
  const float* skip = (const float*)d_in[17];
  const int* src = (const int*)d_in[18];
  const int* dstv = (const int*)d_in[19];
  int N = in_sizes[0] / D;      // 20000
  int E = in_sizes[18];         // 160000

  char* wsb = (char*)d_ws;
  size_t off = 0;
  auto alloc = [&](size_t bytes) { size_t o = off; off += (bytes + 63) & ~(size_t)63; return o; };
  unsigned short* P         = (unsigned short*)(wsb + alloc((size_t)12 * N * D * 2));
  unsigned short* Wt_all    = (unsigned short*)(wsb + alloc((size_t)6 * 16384 * 2));
  float*          bias_all  = (float*)(wsb + alloc((size_t)6 * 128 * 4));
  int*            cnt2      = (int*)(wsb + alloc((size_t)2 * N * 4));   // counts | cursor
  int*            row_start = (int*)(wsb + alloc((size_t)(N + 1) * 4));
  int*            src_sorted= (int*)(wsb + alloc((size_t)E * 4));
  int*            partials  = (int*)(wsb + alloc((size_t)64 * 4));
  unsigned short* hagg      = (unsigned short*)(wsb + alloc((size_t)3 * N * D * 2));
  int* counts = cnt2;
  int* cursor = cnt2 + N;

  hipMemsetAsync(cnt2, 0, (size_t)2 * N * sizeof(int), stream);
  int hist_blocks = (E + 255) / 256;
  k_misc<<<dim3(384 + hist_blocks), 256, 0, stream>>>(
      Wk, bk, Wq, bq, Wv, bv, rel_att, rel_msg, rel_pri, wm0, wm1, wm2,
      Wt_all, bias_all, dstv, counts, E);
  k_proj<<<dim3((N + 63) / 64, 3), 256, 0, stream>>>(
      x0, x1, x2, Wt_all, bias_all, P, N);
  int nb = (N + 1024) / 1024;
  k_scan_part<<<dim3(nb), 1024, 0, stream>>>(counts, row_start, partials, N);
  k_scan_fix<<<dim3(1), 1024, 0, stream>>>(row_start, partials, N, nb);
  k_scatter<<<dim3((E + 255) / 256), 256, 0, stream>>>(dstv, src, row_start, cursor, src_sorted, E);
  k_node<<<dim3((N + 3) / 4), 256, 0, stream>>>(
      P, row_start, src_sorted, hagg, N, E);
  k_out<<<dim3((N + 63) / 64, 3), 256, 0, stream>>>(
      hagg, Wa, ba, x0, x1, x2, skip, (float*)d_out, N);
}